// Round 2
// baseline (1701.287 us; speedup 1.0000x reference)
//
#include <hip/hip_runtime.h>
#include <hip/hip_bf16.h>
#include <cmath>

#define NN   20000   // nodes
#define NE   320000  // edges (before self-loops)
#define IND  256
#define HIDD 64
#define NH   4
#define CD   64
#define HC   256     // NH*CD
#define DFFD 128
#define NL   4

static __device__ __forceinline__ float b2f(__hip_bfloat16 v) { return __bfloat162float(v); }

// dtype-adaptive load (flag: 1 -> float32 buffer, 0 -> bf16 buffer); idx in ELEMENTS
static __device__ __forceinline__ float ldf(const void* __restrict__ p, int idx, int f32) {
    return f32 ? ((const float*)p)[idx] : b2f(((const __hip_bfloat16*)p)[idx]);
}

// Probe dtype of x: even-indexed bf16 halves of an f32 buffer are mantissa garbage
// (|v|>1e4 with p~0.44, occasional NaN); of a genuine bf16 buffer they are N(0,1).
__global__ void detect_dtype(const void* __restrict__ x, int* __restrict__ flag) {
    int c = 0;
    for (int i = threadIdx.x; i < 4096; i += 256) {
        float v = b2f(((const __hip_bfloat16*)x)[2 * i]);
        if (!(fabsf(v) <= 1e4f)) c++;   // counts NaN too
    }
    for (int k = 32; k; k >>= 1) c += __shfl_xor(c, k);
    __shared__ int s[4];
    if ((threadIdx.x & 63) == 0) s[threadIdx.x >> 6] = c;
    __syncthreads();
    if (threadIdx.x == 0) flag[0] = (s[0] + s[1] + s[2] + s[3] > 16) ? 1 : 0;
}

// h[N,64] = (x @ We + be) * 8
__global__ void embed_kernel(const void* __restrict__ x,
                             const void* __restrict__ We,
                             const void* __restrict__ be,
                             float* __restrict__ h, const int* __restrict__ flag) {
    __shared__ float xs[IND];
    const int f32 = flag[0];
    const int i = blockIdx.x, t = threadIdx.x;   // 64 threads
    for (int k = t; k < IND; k += 64) xs[k] = ldf(x, i * IND + k, f32);
    __syncthreads();
    float acc = 0.f;
    for (int k = 0; k < IND; ++k) acc += xs[k] * ldf(We, k * HIDD + t, f32);
    h[i * HIDD + t] = (acc + ldf(be, t, f32)) * 8.0f;
}

__global__ void init_deg(int* __restrict__ deg, int* __restrict__ cursor) {
    int i = blockIdx.x * blockDim.x + threadIdx.x;
    if (i < NN) { deg[i] = 1; cursor[i] = 0; }   // deg starts at 1 for self-loop
}

__global__ void count_edges(const int* __restrict__ ei, int* __restrict__ deg) {
    int e = blockIdx.x * blockDim.x + threadIdx.x;
    if (e < NE) atomicAdd(&deg[ei[NE + e]], 1);
}

// exclusive scan of deg[NN] -> rowptr[NN+1], single block of 1024
__global__ void scan_kernel(const int* __restrict__ deg, int* __restrict__ rowptr) {
    __shared__ int part[1024];
    const int t = threadIdx.x;
    const int CH = (NN + 1023) / 1024;  // 20
    int lo = t * CH, hi = lo + CH; if (hi > NN) hi = NN;
    int s = 0;
    for (int i = lo; i < hi; ++i) s += deg[i];
    part[t] = s;
    __syncthreads();
    for (int off = 1; off < 1024; off <<= 1) {
        int v = 0;
        if (t >= off) v = part[t - off];
        __syncthreads();
        if (t >= off) part[t] += v;
        __syncthreads();
    }
    int base = (t == 0) ? 0 : part[t - 1];
    for (int i = lo; i < hi; ++i) { rowptr[i] = base; base += deg[i]; }
    if (lo <= NN - 1 && NN - 1 < hi) rowptr[NN] = base;
}

__global__ void scatter_edges(const int* __restrict__ ei, const int* __restrict__ rowptr,
                              int* __restrict__ cursor, int* __restrict__ csr_src) {
    int e = blockIdx.x * blockDim.x + threadIdx.x;
    if (e < NE) {
        int s = ei[e], d = ei[NE + e];
        int pos = atomicAdd(&cursor[d], 1);
        csr_src[rowptr[d] + pos] = s;
    } else if (e < NE + NN) {
        int i = e - NE;
        int pos = atomicAdd(&cursor[i], 1);
        csr_src[rowptr[i] + pos] = i;   // self loop
    }
}

// xh[N,256] = h @ Wc[l]; a_s[N,4], a_d[N,4] = per-head attention scalars
// oWc/oAtt: ELEMENT offsets of layer l within Wc / att_src / att_dst
__global__ __launch_bounds__(256) void xh_kernel(
    const float* __restrict__ h, const void* __restrict__ Wc,
    const void* __restrict__ att_src, const void* __restrict__ att_dst,
    float* __restrict__ xh, float* __restrict__ a_s, float* __restrict__ a_d,
    const int* __restrict__ flag, int oWc, int oAtt) {
    __shared__ float hs[HIDD];
    const int f32 = flag[0];
    const int i = blockIdx.x, t = threadIdx.x;   // 256 threads
    if (t < HIDD) hs[t] = h[i * HIDD + t];
    __syncthreads();
    float acc = 0.f;
    for (int k = 0; k < HIDD; ++k) acc += hs[k] * ldf(Wc, oWc + k * HC + t, f32);
    xh[i * HC + t] = acc;
    const int head = t >> 6, lane = t & 63;   // each wave = one head
    float vs = acc * ldf(att_src, oAtt + head * CD + lane, f32);
    float vd = acc * ldf(att_dst, oAtt + head * CD + lane, f32);
    for (int k = 32; k; k >>= 1) { vs += __shfl_xor(vs, k); vd += __shfl_xor(vd, k); }
    if (lane == 0) { a_s[i * NH + head] = vs; a_d[i * NH + head] = vd; }
}

// per dst node: softmax-attention aggregate + FFN + LayerNorm + residual, all fused
__global__ __launch_bounds__(256) void agg_ffn_kernel(
    const float* __restrict__ xh, const float* __restrict__ a_s, const float* __restrict__ a_d,
    const int* __restrict__ rowptr, const int* __restrict__ csr_src,
    const void* __restrict__ bc,  const void* __restrict__ W1,
    const void* __restrict__ b1,  const void* __restrict__ W2,
    const void* __restrict__ b2,  const void* __restrict__ ln_g,
    const void* __restrict__ ln_b, float* __restrict__ h,
    const int* __restrict__ flag, int l) {
    __shared__ float s_adi[NH];
    __shared__ float s_m[NH], s_z[NH];
    __shared__ float s_red[4][NH];
    __shared__ int   s_src[64];
    __shared__ float s_w[64 * NH];
    __shared__ float s_out[HC];
    __shared__ float s_t1[DFFD];

    const int f32 = flag[0];
    const int oBC = l * HC, oW1 = l * HC * DFFD, oB1 = l * DFFD;
    const int oW2 = l * DFFD * HIDD, oB2 = l * HIDD, oLN = l * HIDD;
    const int i = blockIdx.x, t = threadIdx.x;
    const int wave = t >> 6, lane = t & 63;
    const int lo = rowptr[i], hi = rowptr[i + 1];
    if (t < NH) s_adi[t] = a_d[i * NH + t];
    __syncthreads();
    const float ad0 = s_adi[0], ad1 = s_adi[1], ad2 = s_adi[2], ad3 = s_adi[3];
    const float4* as4 = (const float4*)a_s;

    // Phase 1: per-head max of leaky_relu scores
    float m0 = -1e30f, m1 = -1e30f, m2 = -1e30f, m3 = -1e30f;
    for (int j = lo + t; j < hi; j += 256) {
        int s = csr_src[j];
        float4 a = as4[s];
        float e0 = a.x + ad0; e0 = e0 > 0.f ? e0 : 0.2f * e0;
        float e1 = a.y + ad1; e1 = e1 > 0.f ? e1 : 0.2f * e1;
        float e2 = a.z + ad2; e2 = e2 > 0.f ? e2 : 0.2f * e2;
        float e3 = a.w + ad3; e3 = e3 > 0.f ? e3 : 0.2f * e3;
        m0 = fmaxf(m0, e0); m1 = fmaxf(m1, e1); m2 = fmaxf(m2, e2); m3 = fmaxf(m3, e3);
    }
    for (int k = 32; k; k >>= 1) {
        m0 = fmaxf(m0, __shfl_xor(m0, k)); m1 = fmaxf(m1, __shfl_xor(m1, k));
        m2 = fmaxf(m2, __shfl_xor(m2, k)); m3 = fmaxf(m3, __shfl_xor(m3, k));
    }
    if (lane == 0) { s_red[wave][0] = m0; s_red[wave][1] = m1; s_red[wave][2] = m2; s_red[wave][3] = m3; }
    __syncthreads();
    if (t < NH) s_m[t] = fmaxf(fmaxf(s_red[0][t], s_red[1][t]), fmaxf(s_red[2][t], s_red[3][t]));
    __syncthreads();
    const float mm0 = s_m[0], mm1 = s_m[1], mm2 = s_m[2], mm3 = s_m[3];

    // Phase 2: per-head sum of exp(e - m)
    float z0 = 0.f, z1 = 0.f, z2 = 0.f, z3 = 0.f;
    for (int j = lo + t; j < hi; j += 256) {
        int s = csr_src[j];
        float4 a = as4[s];
        float e0 = a.x + ad0; e0 = e0 > 0.f ? e0 : 0.2f * e0;
        float e1 = a.y + ad1; e1 = e1 > 0.f ? e1 : 0.2f * e1;
        float e2 = a.z + ad2; e2 = e2 > 0.f ? e2 : 0.2f * e2;
        float e3 = a.w + ad3; e3 = e3 > 0.f ? e3 : 0.2f * e3;
        z0 += expf(e0 - mm0); z1 += expf(e1 - mm1); z2 += expf(e2 - mm2); z3 += expf(e3 - mm3);
    }
    for (int k = 32; k; k >>= 1) {
        z0 += __shfl_xor(z0, k); z1 += __shfl_xor(z1, k);
        z2 += __shfl_xor(z2, k); z3 += __shfl_xor(z3, k);
    }
    if (lane == 0) { s_red[wave][0] = z0; s_red[wave][1] = z1; s_red[wave][2] = z2; s_red[wave][3] = z3; }
    __syncthreads();
    if (t < NH) s_z[t] = s_red[0][t] + s_red[1][t] + s_red[2][t] + s_red[3][t];
    __syncthreads();

    // Phase 3: weighted aggregation; thread t owns channel t (head = t>>6)
    const int hh = t >> 6;
    float acc = 0.f;
    for (int base0 = lo; base0 < hi; base0 += 64) {
        int n = hi - base0; if (n > 64) n = 64;
        __syncthreads();   // protect s_src/s_w reuse
        const int jl = t >> 2, hq = t & 3;
        if (jl < n) {
            int s = csr_src[base0 + jl];
            if (hq == 0) s_src[jl] = s;
            float e = a_s[s * NH + hq] + s_adi[hq];
            e = e > 0.f ? e : 0.2f * e;
            s_w[jl * NH + hq] = expf(e - s_m[hq]) / (s_z[hq] + 1e-16f);
        }
        __syncthreads();
        for (int j = 0; j < n; ++j)
            acc += xh[(size_t)s_src[j] * HC + t] * s_w[j * NH + hh];
    }
    acc += ldf(bc, oBC + t, f32);
    s_out[t] = acc;
    __syncthreads();

    // FFN: t1 = gelu(out @ W1 + b1)
    if (t < DFFD) {
        float d1 = ldf(b1, oB1 + t, f32);
        for (int k = 0; k < HC; ++k) d1 += s_out[k] * ldf(W1, oW1 + k * DFFD + t, f32);
        s_t1[t] = 0.5f * d1 * (1.f + erff(d1 * 0.70710678118654752f));
    }
    __syncthreads();
    // f = t1 @ W2 + b2; h += layernorm(f)
    if (t < HIDD) {
        float d2 = ldf(b2, oB2 + t, f32);
        for (int k = 0; k < DFFD; ++k) d2 += s_t1[k] * ldf(W2, oW2 + k * HIDD + t, f32);
        float mean = d2;
        for (int k = 32; k; k >>= 1) mean += __shfl_xor(mean, k);
        mean *= (1.0f / 64.0f);
        float dd = d2 - mean;
        float var = dd * dd;
        for (int k = 32; k; k >>= 1) var += __shfl_xor(var, k);
        var *= (1.0f / 64.0f);
        float nrm = dd * rsqrtf(var + 1e-5f);
        h[i * HIDD + t] += nrm * ldf(ln_g, oLN + t, f32) + ldf(ln_b, oLN + t, f32);
    }
}

__global__ void cast_out(const float* __restrict__ h, void* __restrict__ out,
                         const int* __restrict__ flag) {
    const int f32 = flag[0];
    int i = blockIdx.x * blockDim.x + threadIdx.x;
    if (i < NN * HIDD) {
        if (f32) ((float*)out)[i] = h[i];
        else     ((__hip_bfloat16*)out)[i] = __float2bfloat16(h[i]);
    }
}

extern "C" void kernel_launch(void* const* d_in, const int* in_sizes, int n_in,
                              void* d_out, int out_size, void* d_ws, size_t ws_size,
                              hipStream_t stream) {
    const void* x       = d_in[0];
    const int*  ei      = (const int*)d_in[1];
    const void* We      = d_in[2];
    const void* be      = d_in[3];
    const void* Wc      = d_in[4];
    const void* att_src = d_in[5];
    const void* att_dst = d_in[6];
    const void* bc      = d_in[7];
    const void* W1      = d_in[8];
    const void* b1      = d_in[9];
    const void* W2      = d_in[10];
    const void* b2      = d_in[11];
    const void* ln_g    = d_in[12];
    const void* ln_b    = d_in[13];

    char* ws = (char*)d_ws;
    size_t off = 0;
    auto alloc = [&](size_t bytes) -> void* {
        void* p = ws + off; off += (bytes + 255) & ~(size_t)255; return p;
    };
    float* h       = (float*)alloc((size_t)NN * HIDD * 4);
    float* xh      = (float*)alloc((size_t)NN * HC * 4);
    float* a_s     = (float*)alloc((size_t)NN * NH * 4);
    float* a_d     = (float*)alloc((size_t)NN * NH * 4);
    int*   deg     = (int*)alloc((size_t)NN * 4);
    int*   rowptr  = (int*)alloc((size_t)(NN + 1) * 4);
    int*   cursor  = (int*)alloc((size_t)NN * 4);
    int*   csr_src = (int*)alloc((size_t)(NE + NN) * 4);
    int*   flag    = (int*)alloc(256);
    (void)ws_size; (void)in_sizes; (void)n_in; (void)out_size;

    detect_dtype<<<1, 256, 0, stream>>>(x, flag);
    init_deg<<<(NN + 255) / 256, 256, 0, stream>>>(deg, cursor);
    embed_kernel<<<NN, 64, 0, stream>>>(x, We, be, h, flag);
    count_edges<<<(NE + 255) / 256, 256, 0, stream>>>(ei, deg);
    scan_kernel<<<1, 1024, 0, stream>>>(deg, rowptr);
    scatter_edges<<<(NE + NN + 255) / 256, 256, 0, stream>>>(ei, rowptr, cursor, csr_src);

    for (int l = 0; l < NL; ++l) {
        xh_kernel<<<NN, 256, 0, stream>>>(h, Wc, att_src, att_dst, xh, a_s, a_d,
                                          flag, l * HIDD * HC, l * NH * CD);
        agg_ffn_kernel<<<NN, 256, 0, stream>>>(xh, a_s, a_d, rowptr, csr_src,
            bc, W1, b1, W2, b2, ln_g, ln_b, h, flag, l);
    }
    cast_out<<<(NN * HIDD + 255) / 256, 256, 0, stream>>>(h, d_out, flag);
}

// Round 3
// 905.304 us; speedup vs baseline: 1.8792x; 1.8792x over previous
//
#include <hip/hip_runtime.h>
#include <cmath>

#define NN   20000   // nodes
#define NE   320000  // edges (before self-loops)
#define IND  256
#define HIDD 64
#define NH   4
#define CD   64
#define HC   256     // NH*CD
#define DFFD 128
#define NL   4

// All float tensors are float32 (verified R1 vs R2: bf16 interpretation NaN'd,
// runtime-detected f32 path passed; output written as f32 validated clean).

static __device__ __forceinline__ float lrelu(float v) { return v > 0.f ? v : 0.2f * v; }

// ---------------- embed: h[N,64] = (x @ We + be) * 8, 16 nodes/block ----------------
__global__ __launch_bounds__(256) void embed_kernel(const float* __restrict__ x,
                                                    const float* __restrict__ We,
                                                    const float* __restrict__ be,
                                                    float* __restrict__ h) {
    __shared__ float s_x[16 * IND];   // 16KB, layout [nd][k]
    const int base = blockIdx.x * 16, t = threadIdx.x;
    for (int idx = t; idx < 16 * IND; idx += 256)
        s_x[idx] = x[(size_t)base * IND + idx];
    __syncthreads();
    const int c = t & 63, g = t >> 6;   // wave g handles nodes 4g..4g+3, channel c
    float acc[4] = {0.f, 0.f, 0.f, 0.f};
    const float4* sx4 = (const float4*)s_x;
    for (int k4 = 0; k4 < IND / 4; ++k4) {
        float w0 = We[(4 * k4 + 0) * HIDD + c];
        float w1 = We[(4 * k4 + 1) * HIDD + c];
        float w2 = We[(4 * k4 + 2) * HIDD + c];
        float w3 = We[(4 * k4 + 3) * HIDD + c];
#pragma unroll
        for (int i = 0; i < 4; ++i) {
            float4 v = sx4[(4 * g + i) * (IND / 4) + k4];   // wave-uniform -> LDS broadcast
            acc[i] += v.x * w0 + v.y * w1 + v.z * w2 + v.w * w3;
        }
    }
    float bias = be[c];
#pragma unroll
    for (int i = 0; i < 4; ++i)
        h[(size_t)(base + 4 * g + i) * HIDD + c] = (acc[i] + bias) * 8.0f;
}

// ---------------- CSR build ----------------
__global__ void init_deg(int* __restrict__ deg, int* __restrict__ cursor) {
    int i = blockIdx.x * blockDim.x + threadIdx.x;
    if (i < NN) { deg[i] = 1; cursor[i] = 0; }   // self-loop
}

__global__ void count_edges(const int* __restrict__ ei, int* __restrict__ deg) {
    int e = blockIdx.x * blockDim.x + threadIdx.x;
    if (e < NE) atomicAdd(&deg[ei[NE + e]], 1);
}

__global__ void scan_kernel(const int* __restrict__ deg, int* __restrict__ rowptr) {
    __shared__ int part[1024];
    const int t = threadIdx.x;
    const int CH = (NN + 1023) / 1024;
    int lo = t * CH, hi = lo + CH; if (hi > NN) hi = NN;
    int s = 0;
    for (int i = lo; i < hi; ++i) s += deg[i];
    part[t] = s;
    __syncthreads();
    for (int off = 1; off < 1024; off <<= 1) {
        int v = 0;
        if (t >= off) v = part[t - off];
        __syncthreads();
        if (t >= off) part[t] += v;
        __syncthreads();
    }
    int base = (t == 0) ? 0 : part[t - 1];
    for (int i = lo; i < hi; ++i) { rowptr[i] = base; base += deg[i]; }
    if (lo <= NN - 1 && NN - 1 < hi) rowptr[NN] = base;
}

__global__ void scatter_edges(const int* __restrict__ ei, const int* __restrict__ rowptr,
                              int* __restrict__ cursor, int* __restrict__ csr_src) {
    int e = blockIdx.x * blockDim.x + threadIdx.x;
    if (e < NE) {
        int s = ei[e], d = ei[NE + e];
        int pos = atomicAdd(&cursor[d], 1);
        csr_src[rowptr[d] + pos] = s;
    } else if (e < NE + NN) {
        int i = e - NE;
        int pos = atomicAdd(&cursor[i], 1);
        csr_src[rowptr[i] + pos] = i;
    }
}

// ---------------- xh: [N,256] = h @ Wc ; a_s/a_d per-head dots; 8 nodes/block ----------------
__global__ __launch_bounds__(256) void xh_kernel(
    const float* __restrict__ h, const float* __restrict__ Wc,
    const float* __restrict__ att_src, const float* __restrict__ att_dst,
    float* __restrict__ xh, float* __restrict__ a_s, float* __restrict__ a_d) {
    __shared__ float s_h[8 * HIDD];   // 2KB
    const int base = blockIdx.x * 8, t = threadIdx.x;
    for (int idx = t; idx < 8 * HIDD; idx += 256)
        s_h[idx] = h[(size_t)base * HIDD + idx];
    __syncthreads();
    const int lane = t & 63, head = t >> 6;   // channel = t, wave = head
    float acc[8];
#pragma unroll
    for (int i = 0; i < 8; ++i) acc[i] = 0.f;
    const float4* sh4 = (const float4*)s_h;
    for (int k4 = 0; k4 < HIDD / 4; ++k4) {
        float w0 = Wc[(4 * k4 + 0) * HC + t];
        float w1 = Wc[(4 * k4 + 1) * HC + t];
        float w2 = Wc[(4 * k4 + 2) * HC + t];
        float w3 = Wc[(4 * k4 + 3) * HC + t];
#pragma unroll
        for (int i = 0; i < 8; ++i) {
            float4 v = sh4[i * (HIDD / 4) + k4];   // wave-uniform broadcast
            acc[i] += v.x * w0 + v.y * w1 + v.z * w2 + v.w * w3;
        }
    }
    const float asrc = att_src[head * CD + lane];
    const float adst = att_dst[head * CD + lane];
#pragma unroll
    for (int i = 0; i < 8; ++i) {
        xh[(size_t)(base + i) * HC + t] = acc[i];
        float vs = acc[i] * asrc, vd = acc[i] * adst;
        for (int k = 32; k; k >>= 1) { vs += __shfl_xor(vs, k); vd += __shfl_xor(vd, k); }
        if (lane == 0) { a_s[(base + i) * NH + head] = vs; a_d[(base + i) * NH + head] = vd; }
    }
}

// ---------------- agg: per-node softmax attention aggregate -> outb[N,256] ----------------
__global__ __launch_bounds__(256) void agg_kernel(
    const float* __restrict__ xh, const float* __restrict__ a_s, const float* __restrict__ a_d,
    const int* __restrict__ rowptr, const int* __restrict__ csr_src,
    float* __restrict__ outb) {
    __shared__ float  s_red[4][NH];
    __shared__ float  s_m[NH], s_iz[NH];
    __shared__ int    s_src[256];
    __shared__ float  s_w[256 * NH];
    __shared__ float4 s_acc[4][64];

    const int i = blockIdx.x, t = threadIdx.x;
    const int wave = t >> 6, lane = t & 63;
    const int lo = rowptr[i], n = rowptr[i + 1] - lo;
    const float4 ad = ((const float4*)a_d)[i];
    const float4* as4 = (const float4*)a_s;
    const float4* xh4 = (const float4*)xh;

    float4 acc = make_float4(0.f, 0.f, 0.f, 0.f);
    const int hh = lane >> 4;   // head for channels 4*lane..4*lane+3

    if (n <= 256) {
        // ---- fast path: one edge per thread, scores live in registers ----
        float e0 = -1e30f, e1 = -1e30f, e2 = -1e30f, e3 = -1e30f;
        if (t < n) {
            int s = csr_src[lo + t];
            s_src[t] = s;
            float4 a = as4[s];
            e0 = lrelu(a.x + ad.x); e1 = lrelu(a.y + ad.y);
            e2 = lrelu(a.z + ad.z); e3 = lrelu(a.w + ad.w);
        }
        float m0 = e0, m1 = e1, m2 = e2, m3 = e3;
        for (int k = 32; k; k >>= 1) {
            m0 = fmaxf(m0, __shfl_xor(m0, k)); m1 = fmaxf(m1, __shfl_xor(m1, k));
            m2 = fmaxf(m2, __shfl_xor(m2, k)); m3 = fmaxf(m3, __shfl_xor(m3, k));
        }
        if (lane == 0) { s_red[wave][0] = m0; s_red[wave][1] = m1; s_red[wave][2] = m2; s_red[wave][3] = m3; }
        __syncthreads();
        if (t < NH) s_m[t] = fmaxf(fmaxf(s_red[0][t], s_red[1][t]), fmaxf(s_red[2][t], s_red[3][t]));
        __syncthreads();
        const float M0 = s_m[0], M1 = s_m[1], M2 = s_m[2], M3 = s_m[3];
        float p0 = __expf(e0 - M0), p1 = __expf(e1 - M1);
        float p2 = __expf(e2 - M2), p3 = __expf(e3 - M3);   // inactive -> 0
        float z0 = p0, z1 = p1, z2 = p2, z3 = p3;
        for (int k = 32; k; k >>= 1) {
            z0 += __shfl_xor(z0, k); z1 += __shfl_xor(z1, k);
            z2 += __shfl_xor(z2, k); z3 += __shfl_xor(z3, k);
        }
        if (lane == 0) { s_red[wave][0] = z0; s_red[wave][1] = z1; s_red[wave][2] = z2; s_red[wave][3] = z3; }
        __syncthreads();
        if (t < NH) {
            float z = s_red[0][t] + s_red[1][t] + s_red[2][t] + s_red[3][t];
            s_iz[t] = 1.f / (z + 1e-16f);
        }
        __syncthreads();
        if (t < n) {
            float4 w4 = make_float4(p0 * s_iz[0], p1 * s_iz[1], p2 * s_iz[2], p3 * s_iz[3]);
            ((float4*)s_w)[t] = w4;
        }
        __syncthreads();
        // wave w handles edges j = w, w+4, ... ; each lane a float4 of channels
        for (int j = wave; j < n; j += 4) {
            int ss = s_src[j];
            float wgt = s_w[j * 4 + hh];
            float4 v = xh4[(size_t)ss * 64 + lane];
            acc.x += v.x * wgt; acc.y += v.y * wgt; acc.z += v.z * wgt; acc.w += v.w * wgt;
        }
    } else {
        // ---- slow path (deg > 256): chunked, recompute scores ----
        float m0 = -1e30f, m1 = -1e30f, m2 = -1e30f, m3 = -1e30f;
        for (int j = lo + t; j < lo + n; j += 256) {
            int s = csr_src[j];
            float4 a = as4[s];
            m0 = fmaxf(m0, lrelu(a.x + ad.x)); m1 = fmaxf(m1, lrelu(a.y + ad.y));
            m2 = fmaxf(m2, lrelu(a.z + ad.z)); m3 = fmaxf(m3, lrelu(a.w + ad.w));
        }
        for (int k = 32; k; k >>= 1) {
            m0 = fmaxf(m0, __shfl_xor(m0, k)); m1 = fmaxf(m1, __shfl_xor(m1, k));
            m2 = fmaxf(m2, __shfl_xor(m2, k)); m3 = fmaxf(m3, __shfl_xor(m3, k));
        }
        if (lane == 0) { s_red[wave][0] = m0; s_red[wave][1] = m1; s_red[wave][2] = m2; s_red[wave][3] = m3; }
        __syncthreads();
        if (t < NH) s_m[t] = fmaxf(fmaxf(s_red[0][t], s_red[1][t]), fmaxf(s_red[2][t], s_red[3][t]));
        __syncthreads();
        const float M0 = s_m[0], M1 = s_m[1], M2 = s_m[2], M3 = s_m[3];
        float z0 = 0.f, z1 = 0.f, z2 = 0.f, z3 = 0.f;
        for (int j = lo + t; j < lo + n; j += 256) {
            int s = csr_src[j];
            float4 a = as4[s];
            z0 += __expf(lrelu(a.x + ad.x) - M0); z1 += __expf(lrelu(a.y + ad.y) - M1);
            z2 += __expf(lrelu(a.z + ad.z) - M2); z3 += __expf(lrelu(a.w + ad.w) - M3);
        }
        for (int k = 32; k; k >>= 1) {
            z0 += __shfl_xor(z0, k); z1 += __shfl_xor(z1, k);
            z2 += __shfl_xor(z2, k); z3 += __shfl_xor(z3, k);
        }
        if (lane == 0) { s_red[wave][0] = z0; s_red[wave][1] = z1; s_red[wave][2] = z2; s_red[wave][3] = z3; }
        __syncthreads();
        if (t < NH) {
            float z = s_red[0][t] + s_red[1][t] + s_red[2][t] + s_red[3][t];
            s_iz[t] = 1.f / (z + 1e-16f);
        }
        __syncthreads();
        const float IZ0 = s_iz[0], IZ1 = s_iz[1], IZ2 = s_iz[2], IZ3 = s_iz[3];
        for (int cb = 0; cb < n; cb += 256) {
            int nn = n - cb; if (nn > 256) nn = 256;
            __syncthreads();
            if (t < nn) {
                int s = csr_src[lo + cb + t];
                s_src[t] = s;
                float4 a = as4[s];
                float4 w4 = make_float4(__expf(lrelu(a.x + ad.x) - M0) * IZ0,
                                        __expf(lrelu(a.y + ad.y) - M1) * IZ1,
                                        __expf(lrelu(a.z + ad.z) - M2) * IZ2,
                                        __expf(lrelu(a.w + ad.w) - M3) * IZ3);
                ((float4*)s_w)[t] = w4;
            }
            __syncthreads();
            for (int j = wave; j < nn; j += 4) {
                int ss = s_src[j];
                float wgt = s_w[j * 4 + hh];
                float4 v = xh4[(size_t)ss * 64 + lane];
                acc.x += v.x * wgt; acc.y += v.y * wgt; acc.z += v.z * wgt; acc.w += v.w * wgt;
            }
        }
    }

    s_acc[wave][lane] = acc;
    __syncthreads();
    {   // combine 4 wave-partials; thread t owns channel t
        const float* sa = (const float*)s_acc;
        float tot = sa[t] + sa[256 + t] + sa[512 + t] + sa[768 + t];
        outb[(size_t)i * HC + t] = tot;
    }
}

// ---------------- FFN + LayerNorm + residual, 32 nodes/block ----------------
__global__ __launch_bounds__(256) void ffn_kernel(
    const float* __restrict__ outb, const float* __restrict__ bc,
    const float* __restrict__ W1, const float* __restrict__ b1,
    const float* __restrict__ W2, const float* __restrict__ b2,
    const float* __restrict__ ln_g, const float* __restrict__ ln_b,
    float* __restrict__ h) {
    __shared__ float s_in[32 * HC];     // 32KB, [nd][k]
    __shared__ float s_mid[32 * DFFD];  // 16KB, [nd][f]
    const int base = blockIdx.x * 32, t = threadIdx.x;
    for (int idx = t; idx < 32 * HC; idx += 256)
        s_in[idx] = outb[(size_t)base * HC + idx] + bc[idx & (HC - 1)];
    __syncthreads();

    // GEMM1: mid = gelu(in @ W1 + b1). thread: f = t&127, nodes 16g..16g+15
    {
        const int f = t & 127, g = t >> 7;
        float acc[16];
#pragma unroll
        for (int i = 0; i < 16; ++i) acc[i] = 0.f;
        const float4* si4 = (const float4*)s_in;
        for (int k4 = 0; k4 < HC / 4; ++k4) {
            float w0 = W1[(4 * k4 + 0) * DFFD + f];
            float w1 = W1[(4 * k4 + 1) * DFFD + f];
            float w2 = W1[(4 * k4 + 2) * DFFD + f];
            float w3 = W1[(4 * k4 + 3) * DFFD + f];
#pragma unroll
            for (int i = 0; i < 16; ++i) {
                float4 v = si4[(16 * g + i) * (HC / 4) + k4];   // wave-uniform broadcast
                acc[i] += v.x * w0 + v.y * w1 + v.z * w2 + v.w * w3;
            }
        }
        float bb = b1[f];
#pragma unroll
        for (int i = 0; i < 16; ++i) {
            float d = acc[i] + bb;
            s_mid[(16 * g + i) * DFFD + f] = 0.5f * d * (1.f + erff(d * 0.70710678118654752f));
        }
    }
    __syncthreads();

    // GEMM2 + LN: wave w handles nodes 8w..8w+7, lane = channel c
    {
        const int lane = t & 63, w = t >> 6;
        float a2[8];
#pragma unroll
        for (int i = 0; i < 8; ++i) a2[i] = 0.f;
        const float4* sm4 = (const float4*)s_mid;
        for (int k4 = 0; k4 < DFFD / 4; ++k4) {
            float w0 = W2[(4 * k4 + 0) * HIDD + lane];
            float w1 = W2[(4 * k4 + 1) * HIDD + lane];
            float w2 = W2[(4 * k4 + 2) * HIDD + lane];
            float w3 = W2[(4 * k4 + 3) * HIDD + lane];
#pragma unroll
            for (int i = 0; i < 8; ++i) {
                float4 v = sm4[(8 * w + i) * (DFFD / 4) + k4];   // wave-uniform broadcast
                a2[i] += v.x * w0 + v.y * w1 + v.z * w2 + v.w * w3;
            }
        }
        const float b2c = b2[lane], gc = ln_g[lane], bbc = ln_b[lane];
#pragma unroll
        for (int i = 0; i < 8; ++i) {
            float d = a2[i] + b2c;
            float mean = d;
            for (int k = 32; k; k >>= 1) mean += __shfl_xor(mean, k);
            mean *= (1.0f / 64.0f);
            float dd = d - mean;
            float var = dd * dd;
            for (int k = 32; k; k >>= 1) var += __shfl_xor(var, k);
            var *= (1.0f / 64.0f);
            float nrm = dd * rsqrtf(var + 1e-5f);
            h[(size_t)(base + 8 * w + i) * HIDD + lane] += nrm * gc + bbc;
        }
    }
}

__global__ void copy_out(const float* __restrict__ h, float* __restrict__ out) {
    int i = blockIdx.x * blockDim.x + threadIdx.x;
    if (i < NN * HIDD / 4) ((float4*)out)[i] = ((const float4*)h)[i];
}

extern "C" void kernel_launch(void* const* d_in, const int* in_sizes, int n_in,
                              void* d_out, int out_size, void* d_ws, size_t ws_size,
                              hipStream_t stream) {
    const float* x       = (const float*)d_in[0];
    const int*   ei      = (const int*)d_in[1];
    const float* We      = (const float*)d_in[2];
    const float* be      = (const float*)d_in[3];
    const float* Wc      = (const float*)d_in[4];
    const float* att_src = (const float*)d_in[5];
    const float* att_dst = (const float*)d_in[6];
    const float* bc      = (const float*)d_in[7];
    const float* W1      = (const float*)d_in[8];
    const float* b1      = (const float*)d_in[9];
    const float* W2      = (const float*)d_in[10];
    const float* b2      = (const float*)d_in[11];
    const float* ln_g    = (const float*)d_in[12];
    const float* ln_b    = (const float*)d_in[13];

    char* ws = (char*)d_ws;
    size_t off = 0;
    auto alloc = [&](size_t bytes) -> void* {
        void* p = ws + off; off += (bytes + 255) & ~(size_t)255; return p;
    };
    float* h       = (float*)alloc((size_t)NN * HIDD * 4);
    float* xh      = (float*)alloc((size_t)NN * HC * 4);
    float* outb    = (float*)alloc((size_t)NN * HC * 4);
    float* a_s     = (float*)alloc((size_t)NN * NH * 4);
    float* a_d     = (float*)alloc((size_t)NN * NH * 4);
    int*   deg     = (int*)alloc((size_t)NN * 4);
    int*   rowptr  = (int*)alloc((size_t)(NN + 1) * 4);
    int*   cursor  = (int*)alloc((size_t)NN * 4);
    int*   csr_src = (int*)alloc((size_t)(NE + NN) * 4);
    (void)ws_size; (void)in_sizes; (void)n_in; (void)out_size;

    init_deg<<<(NN + 255) / 256, 256, 0, stream>>>(deg, cursor);
    embed_kernel<<<NN / 16, 256, 0, stream>>>(x, We, be, h);
    count_edges<<<(NE + 255) / 256, 256, 0, stream>>>(ei, deg);
    scan_kernel<<<1, 1024, 0, stream>>>(deg, rowptr);
    scatter_edges<<<(NE + NN + 255) / 256, 256, 0, stream>>>(ei, rowptr, cursor, csr_src);

    for (int l = 0; l < NL; ++l) {
        xh_kernel<<<NN / 8, 256, 0, stream>>>(h, Wc + (size_t)l * HIDD * HC,
                                              att_src + (size_t)l * NH * CD,
                                              att_dst + (size_t)l * NH * CD,
                                              xh, a_s, a_d);
        agg_kernel<<<NN, 256, 0, stream>>>(xh, a_s, a_d, rowptr, csr_src, outb);
        ffn_kernel<<<NN / 32, 256, 0, stream>>>(outb, bc + (size_t)l * HC,
            W1 + (size_t)l * HC * DFFD, b1 + (size_t)l * DFFD,
            W2 + (size_t)l * DFFD * HIDD, b2 + (size_t)l * HIDD,
            ln_g + (size_t)l * HIDD, ln_b + (size_t)l * HIDD, h);
    }
    copy_out<<<(NN * HIDD / 4 + 255) / 256, 256, 0, stream>>>(h, (float*)d_out);
}

// Round 4
// 648.886 us; speedup vs baseline: 2.6219x; 1.3952x over previous
//
#include <hip/hip_runtime.h>
#include <cmath>

#define NN   20000   // nodes
#define NE   320000  // edges (before self-loops)
#define IND  256
#define HIDD 64
#define NH   4
#define CD   64
#define HC   256     // NH*CD
#define DFFD 128
#define NL   4

// All float tensors are float32 (verified R1 vs R2). Output f32.

static __device__ __forceinline__ float lrelu(float v) { return v > 0.f ? v : 0.2f * v; }
static __device__ __forceinline__ float wsum(float v) { for (int k = 32; k; k >>= 1) v += __shfl_xor(v, k); return v; }
static __device__ __forceinline__ float wmax(float v) { for (int k = 32; k; k >>= 1) v = fmaxf(v, __shfl_xor(v, k)); return v; }

// ---- ws_all[l][r][k]: r=0..3 -> Wc_head@att_src, r=4..7 -> Wc_head@att_dst ----
// a_s[i,h] = h[i] . ws_all[l][h], a_d[i,h] = h[i] . ws_all[l][4+h]  (exact algebra)
__global__ void ws_kernel(const float* __restrict__ Wc, const float* __restrict__ att_src,
                          const float* __restrict__ att_dst, float* __restrict__ ws_all) {
    int idx = blockIdx.x * 256 + threadIdx.x;   // 0..2047 = L*8*64
    int l = idx >> 9, r = (idx >> 6) & 7, k = idx & 63;
    int hh = r & 3;
    const float* att = ((r & 4) ? att_dst : att_src) + (size_t)l * NH * CD + hh * CD;
    const float* wrow = Wc + (size_t)l * HIDD * HC + (size_t)k * HC + hh * CD;
    float s = 0.f;
    for (int c = 0; c < CD; ++c) s += wrow[c] * att[c];
    ws_all[idx] = s;
}

// ---- embed: h = (x @ We + be) * 8, fused layer-0 attention dots; 16 nodes/block ----
__global__ __launch_bounds__(256) void embed_kernel(const float* __restrict__ x,
                                                    const float* __restrict__ We,
                                                    const float* __restrict__ be,
                                                    const float* __restrict__ ws_all,
                                                    float* __restrict__ h,
                                                    float* __restrict__ a_s, float* __restrict__ a_d) {
    __shared__ float s_x[16 * IND];   // 16KB
    const int base = blockIdx.x * 16, t = threadIdx.x;
    for (int idx = t; idx < 16 * IND / 4; idx += 256)
        ((float4*)s_x)[idx] = ((const float4*)(x + (size_t)base * IND))[idx];
    __syncthreads();
    const int c = t & 63, g = t >> 6;   // wave g: nodes 4g..4g+3, lane = channel c
    float acc[4] = {0.f, 0.f, 0.f, 0.f};
    const float4* sx4 = (const float4*)s_x;
#pragma unroll 2
    for (int k4 = 0; k4 < IND / 4; ++k4) {
        float w0 = We[(4 * k4 + 0) * HIDD + c];
        float w1 = We[(4 * k4 + 1) * HIDD + c];
        float w2 = We[(4 * k4 + 2) * HIDD + c];
        float w3 = We[(4 * k4 + 3) * HIDD + c];
#pragma unroll
        for (int i = 0; i < 4; ++i) {
            float4 v = sx4[(4 * g + i) * (IND / 4) + k4];
            acc[i] += v.x * w0 + v.y * w1 + v.z * w2 + v.w * w3;
        }
    }
    float bias = be[c];
    float wr[8];
#pragma unroll
    for (int r = 0; r < 8; ++r) wr[r] = ws_all[r * 64 + c];   // layer 0
#pragma unroll
    for (int i = 0; i < 4; ++i) {
        int node = base + 4 * g + i;
        float hv = (acc[i] + bias) * 8.0f;
        h[(size_t)node * HIDD + c] = hv;
        float s0 = wsum(hv * wr[0]), s1 = wsum(hv * wr[1]);
        float s2 = wsum(hv * wr[2]), s3 = wsum(hv * wr[3]);
        float s4 = wsum(hv * wr[4]), s5 = wsum(hv * wr[5]);
        float s6 = wsum(hv * wr[6]), s7 = wsum(hv * wr[7]);
        if (c == 0) {
            ((float4*)a_s)[node] = make_float4(s0, s1, s2, s3);
            ((float4*)a_d)[node] = make_float4(s4, s5, s6, s7);
        }
    }
}

// ---------------- CSR build ----------------
__global__ void init_deg(int* __restrict__ deg, int* __restrict__ cursor) {
    int i = blockIdx.x * blockDim.x + threadIdx.x;
    if (i < NN) { deg[i] = 1; cursor[i] = 0; }   // self-loop
}

__global__ void count_edges(const int* __restrict__ ei, int* __restrict__ deg) {
    int e = blockIdx.x * blockDim.x + threadIdx.x;
    if (e < NE) atomicAdd(&deg[ei[NE + e]], 1);
}

__global__ void scan_kernel(const int* __restrict__ deg, int* __restrict__ rowptr) {
    __shared__ int part[1024];
    const int t = threadIdx.x;
    const int CH = (NN + 1023) / 1024;
    int lo = t * CH, hi = lo + CH; if (hi > NN) hi = NN;
    int s = 0;
    for (int i = lo; i < hi; ++i) s += deg[i];
    part[t] = s;
    __syncthreads();
    for (int off = 1; off < 1024; off <<= 1) {
        int v = 0;
        if (t >= off) v = part[t - off];
        __syncthreads();
        if (t >= off) part[t] += v;
        __syncthreads();
    }
    int base = (t == 0) ? 0 : part[t - 1];
    for (int i = lo; i < hi; ++i) { rowptr[i] = base; base += deg[i]; }
    if (lo <= NN - 1 && NN - 1 < hi) rowptr[NN] = base;
}

__global__ void scatter_edges(const int* __restrict__ ei, const int* __restrict__ rowptr,
                              int* __restrict__ cursor, int* __restrict__ csr_src) {
    int e = blockIdx.x * blockDim.x + threadIdx.x;
    if (e < NE) {
        int s = ei[e], d = ei[NE + e];
        int pos = atomicAdd(&cursor[d], 1);
        csr_src[rowptr[d] + pos] = s;
    } else if (e < NE + NN) {
        int i = e - NE;
        int pos = atomicAdd(&cursor[i], 1);
        csr_src[rowptr[i] + pos] = i;
    }
}

// ---- agg: one WAVE per node (wave-synchronous, no barriers); 8 nodes/block ----
// hagg[dst, hh*64+k] = sum_src alpha_hh(src,dst) * h[src,k]
__global__ __launch_bounds__(256) void agg_kernel(
    const float* __restrict__ h, const float* __restrict__ a_s, const float* __restrict__ a_d,
    const int* __restrict__ rowptr, const int* __restrict__ csr_src,
    float* __restrict__ hagg) {
    __shared__ int    s_src[8][64];
    __shared__ float4 s_w[8][64];
    const int t = threadIdx.x, wave = t >> 6, lane = t & 63;
    const float4* as4 = (const float4*)a_s;
#pragma unroll
    for (int nd = 0; nd < 2; ++nd) {
        const int slot = wave * 2 + nd;
        const int i = blockIdx.x * 8 + slot;
        const int lo = rowptr[i], n = rowptr[i + 1] - lo;
        const float4 ad = ((const float4*)a_d)[i];
        float acc0 = 0.f, acc1 = 0.f, acc2 = 0.f, acc3 = 0.f;
        if (n <= 64) {
            // fast path: one edge per lane, scores in registers, single a_s gather
            float e0 = -1e30f, e1 = -1e30f, e2 = -1e30f, e3 = -1e30f;
            if (lane < n) {
                int s = csr_src[lo + lane];
                s_src[slot][lane] = s;
                float4 a = as4[s];
                e0 = lrelu(a.x + ad.x); e1 = lrelu(a.y + ad.y);
                e2 = lrelu(a.z + ad.z); e3 = lrelu(a.w + ad.w);
            }
            float M0 = wmax(e0), M1 = wmax(e1), M2 = wmax(e2), M3 = wmax(e3);
            float p0 = __expf(e0 - M0), p1 = __expf(e1 - M1);
            float p2 = __expf(e2 - M2), p3 = __expf(e3 - M3);   // inactive lanes -> 0
            float iz0 = 1.f / (wsum(p0) + 1e-16f), iz1 = 1.f / (wsum(p1) + 1e-16f);
            float iz2 = 1.f / (wsum(p2) + 1e-16f), iz3 = 1.f / (wsum(p3) + 1e-16f);
            if (lane < n) s_w[slot][lane] = make_float4(p0 * iz0, p1 * iz1, p2 * iz2, p3 * iz3);
            for (int j = 0; j < n; ++j) {
                float hv = h[(size_t)s_src[slot][j] * HIDD + lane];   // 256B coalesced row
                float4 w = s_w[slot][j];                               // b128 broadcast
                acc0 += hv * w.x; acc1 += hv * w.y; acc2 += hv * w.z; acc3 += hv * w.w;
            }
        } else {
            // slow path (deg > 64): chunked two-pass softmax, recompute scores
            float m0 = -1e30f, m1 = -1e30f, m2 = -1e30f, m3 = -1e30f;
            for (int j = lane; j < n; j += 64) {
                int s = csr_src[lo + j];
                float4 a = as4[s];
                m0 = fmaxf(m0, lrelu(a.x + ad.x)); m1 = fmaxf(m1, lrelu(a.y + ad.y));
                m2 = fmaxf(m2, lrelu(a.z + ad.z)); m3 = fmaxf(m3, lrelu(a.w + ad.w));
            }
            m0 = wmax(m0); m1 = wmax(m1); m2 = wmax(m2); m3 = wmax(m3);
            float z0 = 0.f, z1 = 0.f, z2 = 0.f, z3 = 0.f;
            for (int j = lane; j < n; j += 64) {
                int s = csr_src[lo + j];
                float4 a = as4[s];
                z0 += __expf(lrelu(a.x + ad.x) - m0); z1 += __expf(lrelu(a.y + ad.y) - m1);
                z2 += __expf(lrelu(a.z + ad.z) - m2); z3 += __expf(lrelu(a.w + ad.w) - m3);
            }
            float iz0 = 1.f / (wsum(z0) + 1e-16f), iz1 = 1.f / (wsum(z1) + 1e-16f);
            float iz2 = 1.f / (wsum(z2) + 1e-16f), iz3 = 1.f / (wsum(z3) + 1e-16f);
            for (int cb = 0; cb < n; cb += 64) {
                int nn = n - cb; if (nn > 64) nn = 64;
                if (lane < nn) {
                    int s = csr_src[lo + cb + lane];
                    s_src[slot][lane] = s;
                    float4 a = as4[s];
                    s_w[slot][lane] = make_float4(__expf(lrelu(a.x + ad.x) - m0) * iz0,
                                                  __expf(lrelu(a.y + ad.y) - m1) * iz1,
                                                  __expf(lrelu(a.z + ad.z) - m2) * iz2,
                                                  __expf(lrelu(a.w + ad.w) - m3) * iz3);
                }
                for (int j = 0; j < nn; ++j) {
                    float hv = h[(size_t)s_src[slot][j] * HIDD + lane];
                    float4 w = s_w[slot][j];
                    acc0 += hv * w.x; acc1 += hv * w.y; acc2 += hv * w.z; acc3 += hv * w.w;
                }
            }
        }
        float* hg = hagg + (size_t)i * HC;
        hg[0 * 64 + lane] = acc0; hg[1 * 64 + lane] = acc1;
        hg[2 * 64 + lane] = acc2; hg[3 * 64 + lane] = acc3;
    }
}

// ---- ffn: out-GEMM (per-head hagg@Wc + bc) + FFN + LN + residual + next-layer attdots ----
// 16 nodes/block, 1250 blocks. LDS 40KB.
__global__ __launch_bounds__(256) void ffn_kernel(
    const float* __restrict__ hagg, const float* __restrict__ Wc, const float* __restrict__ bc,
    const float* __restrict__ W1, const float* __restrict__ b1,
    const float* __restrict__ W2, const float* __restrict__ b2,
    const float* __restrict__ ln_g, const float* __restrict__ ln_b,
    const float* __restrict__ ws_next,
    float* __restrict__ h, float* __restrict__ a_s, float* __restrict__ a_d) {
    __shared__ float s_hagg[16 * HC];   // 16KB
    __shared__ float s_in[16 * HC];     // 16KB
    __shared__ float s_mid[16 * DFFD];  // 8KB
    const int base = blockIdx.x * 16, t = threadIdx.x;
    for (int idx = t; idx < 16 * HC / 4; idx += 256)
        ((float4*)s_hagg)[idx] = ((const float4*)(hagg + (size_t)base * HC))[idx];
    __syncthreads();

    // GEMM0: in[node, t] = sum_k hagg[node, hh*64+k] * Wc[k, t] + bc[t]   (hh = t>>6)
    {
        const int hh = t >> 6;
        float acc[16];
#pragma unroll
        for (int i = 0; i < 16; ++i) acc[i] = 0.f;
        const float4* sh4 = (const float4*)s_hagg;
#pragma unroll 2
        for (int k4 = 0; k4 < 16; ++k4) {
            float w0 = Wc[(4 * k4 + 0) * HC + t];
            float w1 = Wc[(4 * k4 + 1) * HC + t];
            float w2 = Wc[(4 * k4 + 2) * HC + t];
            float w3 = Wc[(4 * k4 + 3) * HC + t];
#pragma unroll
            for (int i = 0; i < 16; ++i) {
                float4 v = sh4[i * 64 + hh * 16 + k4];   // wave-uniform broadcast
                acc[i] += v.x * w0 + v.y * w1 + v.z * w2 + v.w * w3;
            }
        }
        float bb = bc[t];
#pragma unroll
        for (int i = 0; i < 16; ++i) s_in[i * HC + t] = acc[i] + bb;
    }
    __syncthreads();

    // GEMM1: mid = gelu(in @ W1 + b1); f = t&127, g = t>>7 -> 8 nodes each
    {
        const int f = t & 127, g = t >> 7;
        float acc[8];
#pragma unroll
        for (int i = 0; i < 8; ++i) acc[i] = 0.f;
        const float4* si4 = (const float4*)s_in;
#pragma unroll 4
        for (int k4 = 0; k4 < 64; ++k4) {
            float w0 = W1[(4 * k4 + 0) * DFFD + f];
            float w1 = W1[(4 * k4 + 1) * DFFD + f];
            float w2 = W1[(4 * k4 + 2) * DFFD + f];
            float w3 = W1[(4 * k4 + 3) * DFFD + f];
#pragma unroll
            for (int i = 0; i < 8; ++i) {
                float4 v = si4[(8 * g + i) * 64 + k4];
                acc[i] += v.x * w0 + v.y * w1 + v.z * w2 + v.w * w3;
            }
        }
        float bb = b1[f];
#pragma unroll
        for (int i = 0; i < 8; ++i) {
            float d = acc[i] + bb;
            s_mid[(8 * g + i) * DFFD + f] = 0.5f * d * (1.f + erff(d * 0.70710678118654752f));
        }
    }
    __syncthreads();

    // GEMM2 + LN + residual + attdots for next layer; wave w -> nodes 4w..4w+3, lane = channel
    {
        const int lane = t & 63, w = t >> 6;
        float acc[4];
#pragma unroll
        for (int i = 0; i < 4; ++i) acc[i] = 0.f;
        const float4* sm4 = (const float4*)s_mid;
#pragma unroll 4
        for (int k4 = 0; k4 < 32; ++k4) {
            float w0 = W2[(4 * k4 + 0) * HIDD + lane];
            float w1 = W2[(4 * k4 + 1) * HIDD + lane];
            float w2 = W2[(4 * k4 + 2) * HIDD + lane];
            float w3 = W2[(4 * k4 + 3) * HIDD + lane];
#pragma unroll
            for (int i = 0; i < 4; ++i) {
                float4 v = sm4[(4 * w + i) * 32 + k4];
                acc[i] += v.x * w0 + v.y * w1 + v.z * w2 + v.w * w3;
            }
        }
        const float b2c = b2[lane], gc = ln_g[lane], bbc = ln_b[lane];
        float wr[8];
#pragma unroll
        for (int r = 0; r < 8; ++r) wr[r] = 0.f;
        if (ws_next) {
#pragma unroll
            for (int r = 0; r < 8; ++r) wr[r] = ws_next[r * 64 + lane];
        }
#pragma unroll
        for (int i = 0; i < 4; ++i) {
            int node = base + 4 * w + i;
            float d = acc[i] + b2c;
            float mean = wsum(d) * (1.0f / 64.0f);
            float dd = d - mean;
            float var = wsum(dd * dd) * (1.0f / 64.0f);
            float hv = h[(size_t)node * HIDD + lane] + dd * rsqrtf(var + 1e-5f) * gc + bbc;
            h[(size_t)node * HIDD + lane] = hv;
            if (ws_next) {
                float s0 = wsum(hv * wr[0]), s1 = wsum(hv * wr[1]);
                float s2 = wsum(hv * wr[2]), s3 = wsum(hv * wr[3]);
                float s4 = wsum(hv * wr[4]), s5 = wsum(hv * wr[5]);
                float s6 = wsum(hv * wr[6]), s7 = wsum(hv * wr[7]);
                if (lane == 0) {
                    ((float4*)a_s)[node] = make_float4(s0, s1, s2, s3);
                    ((float4*)a_d)[node] = make_float4(s4, s5, s6, s7);
                }
            }
        }
    }
}

__global__ void copy_out(const float* __restrict__ h, float* __restrict__ out) {
    int i = blockIdx.x * blockDim.x + threadIdx.x;
    if (i < NN * HIDD / 4) ((float4*)out)[i] = ((const float4*)h)[i];
}

extern "C" void kernel_launch(void* const* d_in, const int* in_sizes, int n_in,
                              void* d_out, int out_size, void* d_ws, size_t ws_size,
                              hipStream_t stream) {
    const float* x       = (const float*)d_in[0];
    const int*   ei      = (const int*)d_in[1];
    const float* We      = (const float*)d_in[2];
    const float* be      = (const float*)d_in[3];
    const float* Wc      = (const float*)d_in[4];
    const float* att_src = (const float*)d_in[5];
    const float* att_dst = (const float*)d_in[6];
    const float* bc      = (const float*)d_in[7];
    const float* W1      = (const float*)d_in[8];
    const float* b1      = (const float*)d_in[9];
    const float* W2      = (const float*)d_in[10];
    const float* b2      = (const float*)d_in[11];
    const float* ln_g    = (const float*)d_in[12];
    const float* ln_b    = (const float*)d_in[13];

    char* ws = (char*)d_ws;
    size_t off = 0;
    auto alloc = [&](size_t bytes) -> void* {
        void* p = ws + off; off += (bytes + 255) & ~(size_t)255; return p;
    };
    float* h       = (float*)alloc((size_t)NN * HIDD * 4);
    float* hagg    = (float*)alloc((size_t)NN * HC * 4);
    float* a_s     = (float*)alloc((size_t)NN * NH * 4);
    float* a_d     = (float*)alloc((size_t)NN * NH * 4);
    float* ws_all  = (float*)alloc((size_t)NL * 8 * 64 * 4);
    int*   deg     = (int*)alloc((size_t)NN * 4);
    int*   rowptr  = (int*)alloc((size_t)(NN + 1) * 4);
    int*   cursor  = (int*)alloc((size_t)NN * 4);
    int*   csr_src = (int*)alloc((size_t)(NE + NN) * 4);
    (void)ws_size; (void)in_sizes; (void)n_in; (void)out_size;

    ws_kernel<<<8, 256, 0, stream>>>(Wc, att_src, att_dst, ws_all);
    init_deg<<<(NN + 255) / 256, 256, 0, stream>>>(deg, cursor);
    embed_kernel<<<NN / 16, 256, 0, stream>>>(x, We, be, ws_all, h, a_s, a_d);
    count_edges<<<(NE + 255) / 256, 256, 0, stream>>>(ei, deg);
    scan_kernel<<<1, 1024, 0, stream>>>(deg, rowptr);
    scatter_edges<<<(NE + NN + 255) / 256, 256, 0, stream>>>(ei, rowptr, cursor, csr_src);

    for (int l = 0; l < NL; ++l) {
        agg_kernel<<<NN / 8, 256, 0, stream>>>(h, a_s, a_d, rowptr, csr_src, hagg);
        ffn_kernel<<<NN / 16, 256, 0, stream>>>(hagg,
            Wc + (size_t)l * HIDD * HC, bc + (size_t)l * HC,
            W1 + (size_t)l * HC * DFFD, b1 + (size_t)l * DFFD,
            W2 + (size_t)l * DFFD * HIDD, b2 + (size_t)l * HIDD,
            ln_g + (size_t)l * HIDD, ln_b + (size_t)l * HIDD,
            (l + 1 < NL) ? (ws_all + (size_t)(l + 1) * 8 * 64) : (const float*)nullptr,
            h, a_s, a_d);
    }
    copy_out<<<(NN * HIDD / 4 + 255) / 256, 256, 0, stream>>>(h, (float*)d_out);
}

// Round 5
// 592.789 us; speedup vs baseline: 2.8700x; 1.0946x over previous
//
#include <hip/hip_runtime.h>
#include <cmath>

#define NN   20000   // nodes
#define NE   320000  // edges (before self-loops)
#define IND  256
#define HIDD 64
#define NH   4
#define CD   64
#define HC   256     // NH*CD
#define DFFD 128
#define NL   4

// All float tensors are float32 (verified R1 vs R2). Output f32.

static __device__ __forceinline__ float lrelu(float v) { return v > 0.f ? v : 0.2f * v; }
static __device__ __forceinline__ float wsum(float v) { for (int k = 32; k; k >>= 1) v += __shfl_xor(v, k); return v; }
static __device__ __forceinline__ float wmax(float v) { for (int k = 32; k; k >>= 1) v = fmaxf(v, __shfl_xor(v, k)); return v; }

// ---- ws_all[l][r][k]: r=0..3 -> Wc_head@att_src, r=4..7 -> Wc_head@att_dst ----
__global__ void ws_kernel(const float* __restrict__ Wc, const float* __restrict__ att_src,
                          const float* __restrict__ att_dst, float* __restrict__ ws_all) {
    int idx = blockIdx.x * 256 + threadIdx.x;   // 0..2047 = L*8*64
    int l = idx >> 9, r = (idx >> 6) & 7, k = idx & 63;
    int hh = r & 3;
    const float* att = ((r & 4) ? att_dst : att_src) + (size_t)l * NH * CD + hh * CD;
    const float* wrow = Wc + (size_t)l * HIDD * HC + (size_t)k * HC + hh * CD;
    float s = 0.f;
    for (int c = 0; c < CD; ++c) s += wrow[c] * att[c];
    ws_all[idx] = s;
}

// ---- embed: h = (x @ We + be) * 8, fused layer-0 attention dots; 16 nodes/block ----
__global__ __launch_bounds__(256) void embed_kernel(const float* __restrict__ x,
                                                    const float* __restrict__ We,
                                                    const float* __restrict__ be,
                                                    const float* __restrict__ ws_all,
                                                    float* __restrict__ h,
                                                    float* __restrict__ a_s, float* __restrict__ a_d) {
    __shared__ float s_x[16 * IND];   // 16KB
    const int base = blockIdx.x * 16, t = threadIdx.x;
    for (int idx = t; idx < 16 * IND / 4; idx += 256)
        ((float4*)s_x)[idx] = ((const float4*)(x + (size_t)base * IND))[idx];
    __syncthreads();
    const int c = t & 63, g = t >> 6;   // wave g: nodes 4g..4g+3, lane = channel c
    float acc[4] = {0.f, 0.f, 0.f, 0.f};
    const float4* sx4 = (const float4*)s_x;
#pragma unroll 2
    for (int k4 = 0; k4 < IND / 4; ++k4) {
        float w0 = We[(4 * k4 + 0) * HIDD + c];
        float w1 = We[(4 * k4 + 1) * HIDD + c];
        float w2 = We[(4 * k4 + 2) * HIDD + c];
        float w3 = We[(4 * k4 + 3) * HIDD + c];
#pragma unroll
        for (int i = 0; i < 4; ++i) {
            float4 v = sx4[(4 * g + i) * (IND / 4) + k4];
            acc[i] += v.x * w0 + v.y * w1 + v.z * w2 + v.w * w3;
        }
    }
    float bias = be[c];
    float wr[8];
#pragma unroll
    for (int r = 0; r < 8; ++r) wr[r] = ws_all[r * 64 + c];   // layer 0
#pragma unroll
    for (int i = 0; i < 4; ++i) {
        int node = base + 4 * g + i;
        float hv = (acc[i] + bias) * 8.0f;
        h[(size_t)node * HIDD + c] = hv;
        float s0 = wsum(hv * wr[0]), s1 = wsum(hv * wr[1]);
        float s2 = wsum(hv * wr[2]), s3 = wsum(hv * wr[3]);
        float s4 = wsum(hv * wr[4]), s5 = wsum(hv * wr[5]);
        float s6 = wsum(hv * wr[6]), s7 = wsum(hv * wr[7]);
        if (c == 0) {
            ((float4*)a_s)[node] = make_float4(s0, s1, s2, s3);
            ((float4*)a_d)[node] = make_float4(s4, s5, s6, s7);
        }
    }
}

// ---------------- CSR build ----------------
__global__ void init_deg(int* __restrict__ deg, int* __restrict__ cursor) {
    int i = blockIdx.x * blockDim.x + threadIdx.x;
    if (i < NN) { deg[i] = 1; cursor[i] = 0; }   // self-loop
}

__global__ void count_edges(const int* __restrict__ ei, int* __restrict__ deg) {
    int e = blockIdx.x * blockDim.x + threadIdx.x;
    if (e < NE) atomicAdd(&deg[ei[NE + e]], 1);
}

__global__ void scan_kernel(const int* __restrict__ deg, int* __restrict__ rowptr) {
    __shared__ int part[1024];
    const int t = threadIdx.x;
    const int CH = (NN + 1023) / 1024;
    int lo = t * CH, hi = lo + CH; if (hi > NN) hi = NN;
    int s = 0;
    for (int i = lo; i < hi; ++i) s += deg[i];
    part[t] = s;
    __syncthreads();
    for (int off = 1; off < 1024; off <<= 1) {
        int v = 0;
        if (t >= off) v = part[t - off];
        __syncthreads();
        if (t >= off) part[t] += v;
        __syncthreads();
    }
    int base = (t == 0) ? 0 : part[t - 1];
    for (int i = lo; i < hi; ++i) { rowptr[i] = base; base += deg[i]; }
    if (lo <= NN - 1 && NN - 1 < hi) rowptr[NN] = base;
}

__global__ void scatter_edges(const int* __restrict__ ei, const int* __restrict__ rowptr,
                              int* __restrict__ cursor, int* __restrict__ csr_src) {
    int e = blockIdx.x * blockDim.x + threadIdx.x;
    if (e < NE) {
        int s = ei[e], d = ei[NE + e];
        int pos = atomicAdd(&cursor[d], 1);
        csr_src[rowptr[d] + pos] = s;
    } else if (e < NE + NN) {
        int i = e - NE;
        int pos = atomicAdd(&cursor[i], 1);
        csr_src[rowptr[i] + pos] = i;
    }
}

// ---- agg: one WAVE per node; 8 nodes/block; 4-deep MLP in the gather loop ----
__global__ __launch_bounds__(256) void agg_kernel(
    const float* __restrict__ h, const float* __restrict__ a_s, const float* __restrict__ a_d,
    const int* __restrict__ rowptr, const int* __restrict__ csr_src,
    float* __restrict__ hagg) {
    __shared__ int    s_src[8][64];
    __shared__ float4 s_w[8][64];
    const int t = threadIdx.x, wave = t >> 6, lane = t & 63;
    const float4* as4 = (const float4*)a_s;
#pragma unroll
    for (int nd = 0; nd < 2; ++nd) {
        const int slot = wave * 2 + nd;
        const int i = blockIdx.x * 8 + slot;
        const int lo = rowptr[i], n = rowptr[i + 1] - lo;
        const float4 ad = ((const float4*)a_d)[i];
        float acc0 = 0.f, acc1 = 0.f, acc2 = 0.f, acc3 = 0.f;
        if (n <= 64) {
            float e0 = -1e30f, e1 = -1e30f, e2 = -1e30f, e3 = -1e30f;
            if (lane < n) {
                int s = csr_src[lo + lane];
                s_src[slot][lane] = s;
                float4 a = as4[s];
                e0 = lrelu(a.x + ad.x); e1 = lrelu(a.y + ad.y);
                e2 = lrelu(a.z + ad.z); e3 = lrelu(a.w + ad.w);
            }
            float M0 = wmax(e0), M1 = wmax(e1), M2 = wmax(e2), M3 = wmax(e3);
            float p0 = __expf(e0 - M0), p1 = __expf(e1 - M1);
            float p2 = __expf(e2 - M2), p3 = __expf(e3 - M3);
            float iz0 = 1.f / (wsum(p0) + 1e-16f), iz1 = 1.f / (wsum(p1) + 1e-16f);
            float iz2 = 1.f / (wsum(p2) + 1e-16f), iz3 = 1.f / (wsum(p3) + 1e-16f);
            if (lane < n) s_w[slot][lane] = make_float4(p0 * iz0, p1 * iz1, p2 * iz2, p3 * iz3);
            int j = 0;
            for (; j + 4 <= n; j += 4) {   // 4 independent h-row loads in flight
                int  q0 = s_src[slot][j],     q1 = s_src[slot][j + 1];
                int  q2 = s_src[slot][j + 2], q3 = s_src[slot][j + 3];
                float h0 = h[(size_t)q0 * HIDD + lane], h1 = h[(size_t)q1 * HIDD + lane];
                float h2 = h[(size_t)q2 * HIDD + lane], h3 = h[(size_t)q3 * HIDD + lane];
                float4 w0 = s_w[slot][j],     w1 = s_w[slot][j + 1];
                float4 w2 = s_w[slot][j + 2], w3 = s_w[slot][j + 3];
                acc0 += h0 * w0.x + h1 * w1.x + h2 * w2.x + h3 * w3.x;
                acc1 += h0 * w0.y + h1 * w1.y + h2 * w2.y + h3 * w3.y;
                acc2 += h0 * w0.z + h1 * w1.z + h2 * w2.z + h3 * w3.z;
                acc3 += h0 * w0.w + h1 * w1.w + h2 * w2.w + h3 * w3.w;
            }
            for (; j < n; ++j) {
                float hv = h[(size_t)s_src[slot][j] * HIDD + lane];
                float4 w = s_w[slot][j];
                acc0 += hv * w.x; acc1 += hv * w.y; acc2 += hv * w.z; acc3 += hv * w.w;
            }
        } else {
            float m0 = -1e30f, m1 = -1e30f, m2 = -1e30f, m3 = -1e30f;
            for (int j = lane; j < n; j += 64) {
                int s = csr_src[lo + j];
                float4 a = as4[s];
                m0 = fmaxf(m0, lrelu(a.x + ad.x)); m1 = fmaxf(m1, lrelu(a.y + ad.y));
                m2 = fmaxf(m2, lrelu(a.z + ad.z)); m3 = fmaxf(m3, lrelu(a.w + ad.w));
            }
            m0 = wmax(m0); m1 = wmax(m1); m2 = wmax(m2); m3 = wmax(m3);
            float z0 = 0.f, z1 = 0.f, z2 = 0.f, z3 = 0.f;
            for (int j = lane; j < n; j += 64) {
                int s = csr_src[lo + j];
                float4 a = as4[s];
                z0 += __expf(lrelu(a.x + ad.x) - m0); z1 += __expf(lrelu(a.y + ad.y) - m1);
                z2 += __expf(lrelu(a.z + ad.z) - m2); z3 += __expf(lrelu(a.w + ad.w) - m3);
            }
            float iz0 = 1.f / (wsum(z0) + 1e-16f), iz1 = 1.f / (wsum(z1) + 1e-16f);
            float iz2 = 1.f / (wsum(z2) + 1e-16f), iz3 = 1.f / (wsum(z3) + 1e-16f);
            for (int cb = 0; cb < n; cb += 64) {
                int nn = n - cb; if (nn > 64) nn = 64;
                if (lane < nn) {
                    int s = csr_src[lo + cb + lane];
                    s_src[slot][lane] = s;
                    float4 a = as4[s];
                    s_w[slot][lane] = make_float4(__expf(lrelu(a.x + ad.x) - m0) * iz0,
                                                  __expf(lrelu(a.y + ad.y) - m1) * iz1,
                                                  __expf(lrelu(a.z + ad.z) - m2) * iz2,
                                                  __expf(lrelu(a.w + ad.w) - m3) * iz3);
                }
                int j = 0;
                for (; j + 4 <= nn; j += 4) {
                    int  q0 = s_src[slot][j],     q1 = s_src[slot][j + 1];
                    int  q2 = s_src[slot][j + 2], q3 = s_src[slot][j + 3];
                    float h0 = h[(size_t)q0 * HIDD + lane], h1 = h[(size_t)q1 * HIDD + lane];
                    float h2 = h[(size_t)q2 * HIDD + lane], h3 = h[(size_t)q3 * HIDD + lane];
                    float4 w0 = s_w[slot][j],     w1 = s_w[slot][j + 1];
                    float4 w2 = s_w[slot][j + 2], w3 = s_w[slot][j + 3];
                    acc0 += h0 * w0.x + h1 * w1.x + h2 * w2.x + h3 * w3.x;
                    acc1 += h0 * w0.y + h1 * w1.y + h2 * w2.y + h3 * w3.y;
                    acc2 += h0 * w0.z + h1 * w1.z + h2 * w2.z + h3 * w3.z;
                    acc3 += h0 * w0.w + h1 * w1.w + h2 * w2.w + h3 * w3.w;
                }
                for (; j < nn; ++j) {
                    float hv = h[(size_t)s_src[slot][j] * HIDD + lane];
                    float4 w = s_w[slot][j];
                    acc0 += hv * w.x; acc1 += hv * w.y; acc2 += hv * w.z; acc3 += hv * w.w;
                }
            }
        }
        float* hg = hagg + (size_t)i * HC;
        hg[0 * 64 + lane] = acc0; hg[1 * 64 + lane] = acc1;
        hg[2 * 64 + lane] = acc2; hg[3 * 64 + lane] = acc3;
    }
}

// ---- ffn: GEMM0 (hagg@Wc+bc) -> GEMM1 (LDS-staged W1, gelu) -> GEMM2+LN+residual ----
// 16 nodes/block. LDS: s_in 16KB + s_buf 32KB (hagg -> W1 tile -> mid) = 48KB -> 3 blk/CU.
__global__ __launch_bounds__(256, 3) void ffn_kernel(
    const float* __restrict__ hagg, const float* __restrict__ Wc, const float* __restrict__ bc,
    const float* __restrict__ W1, const float* __restrict__ b1,
    const float* __restrict__ W2, const float* __restrict__ b2,
    const float* __restrict__ ln_g, const float* __restrict__ ln_b,
    const float* __restrict__ ws_next,
    float* __restrict__ h, float* __restrict__ a_s, float* __restrict__ a_d) {
    __shared__ float s_buf[8192];       // 32KB: hagg(16KB) -> W1 k-tile(32KB) -> mid(8KB)
    __shared__ float s_in[16 * HC];     // 16KB
    const int base = blockIdx.x * 16, t = threadIdx.x;
    for (int idx = t; idx < 16 * HC / 4; idx += 256)
        ((float4*)s_buf)[idx] = ((const float4*)(hagg + (size_t)base * HC))[idx];
    __syncthreads();

    // GEMM0: s_in[i][c] = sum_k s_hagg[i][(c>>6)*64+k] * Wc[k][c] + bc[c]
    // thread: c4 = 4*(t&63) (dwordx4 weights, lane-contiguous 1KB), 4 nodes (t>>6)
    {
        const int cq = t & 63, ng = t >> 6;
        const int c0 = cq * 4, hh = c0 >> 6;
        float4 acc[4];
#pragma unroll
        for (int i = 0; i < 4; ++i) acc[i] = make_float4(0.f, 0.f, 0.f, 0.f);
        const float* wbase = Wc + c0;
        const float4* sh4 = (const float4*)s_buf;
#pragma unroll 2
        for (int k4 = 0; k4 < 16; ++k4) {
            float4 w0 = *(const float4*)(wbase + (size_t)(4 * k4 + 0) * HC);
            float4 w1 = *(const float4*)(wbase + (size_t)(4 * k4 + 1) * HC);
            float4 w2 = *(const float4*)(wbase + (size_t)(4 * k4 + 2) * HC);
            float4 w3 = *(const float4*)(wbase + (size_t)(4 * k4 + 3) * HC);
#pragma unroll
            for (int i = 0; i < 4; ++i) {
                float4 v = sh4[(4 * ng + i) * 64 + hh * 16 + k4];
                acc[i].x += v.x * w0.x + v.y * w1.x + v.z * w2.x + v.w * w3.x;
                acc[i].y += v.x * w0.y + v.y * w1.y + v.z * w2.y + v.w * w3.y;
                acc[i].z += v.x * w0.z + v.y * w1.z + v.z * w2.z + v.w * w3.z;
                acc[i].w += v.x * w0.w + v.y * w1.w + v.z * w2.w + v.w * w3.w;
            }
        }
        float4 bb = *(const float4*)(bc + c0);
#pragma unroll
        for (int i = 0; i < 4; ++i) {
            float4 r = make_float4(acc[i].x + bb.x, acc[i].y + bb.y,
                                   acc[i].z + bb.z, acc[i].w + bb.w);
            *(float4*)(s_in + (size_t)(4 * ng + i) * HC + c0) = r;
        }
    }

    // GEMM1: mid = gelu(in @ W1 + b1), W1 staged in LDS k-tiles of 64 (once from L2)
    // thread: f = t&127, 8 nodes (t>>7)
    float acc1[8];
#pragma unroll
    for (int i = 0; i < 8; ++i) acc1[i] = 0.f;
    {
        const int f = t & 127, g = t >> 7;
        const float4* si4 = (const float4*)s_in;
        for (int kt = 0; kt < 4; ++kt) {
            __syncthreads();   // prior s_buf readers done (GEMM0 / previous tile)
            const float4* gsrc = (const float4*)(W1 + (size_t)kt * 64 * DFFD);
            for (int idx = t; idx < 2048; idx += 256)
                ((float4*)s_buf)[idx] = gsrc[idx];
            __syncthreads();
#pragma unroll 4
            for (int k4 = 0; k4 < 16; ++k4) {
                float w0 = s_buf[(4 * k4 + 0) * DFFD + f];   // bank=f%32: 2-way, free
                float w1 = s_buf[(4 * k4 + 1) * DFFD + f];
                float w2 = s_buf[(4 * k4 + 2) * DFFD + f];
                float w3 = s_buf[(4 * k4 + 3) * DFFD + f];
#pragma unroll
                for (int i = 0; i < 8; ++i) {
                    float4 v = si4[(8 * g + i) * 64 + kt * 16 + k4];   // wave-uniform
                    acc1[i] += v.x * w0 + v.y * w1 + v.z * w2 + v.w * w3;
                }
            }
        }
        __syncthreads();
        float bb = b1[f];
#pragma unroll
        for (int i = 0; i < 8; ++i) {
            float d = acc1[i] + bb;
            s_buf[(8 * g + i) * DFFD + f] = 0.5f * d * (1.f + erff(d * 0.70710678118654752f));
        }
    }
    __syncthreads();

    // GEMM2 + LN + residual + next-layer attdots; wave w -> nodes 4w..4w+3, lane = channel
    {
        const int lane = t & 63, w = t >> 6;
        float acc[4];
#pragma unroll
        for (int i = 0; i < 4; ++i) acc[i] = 0.f;
        const float4* sm4 = (const float4*)s_buf;
#pragma unroll 4
        for (int k4 = 0; k4 < 32; ++k4) {
            float w0 = W2[(4 * k4 + 0) * HIDD + lane];
            float w1 = W2[(4 * k4 + 1) * HIDD + lane];
            float w2 = W2[(4 * k4 + 2) * HIDD + lane];
            float w3 = W2[(4 * k4 + 3) * HIDD + lane];
#pragma unroll
            for (int i = 0; i < 4; ++i) {
                float4 v = sm4[(4 * w + i) * 32 + k4];   // wave-uniform
                acc[i] += v.x * w0 + v.y * w1 + v.z * w2 + v.w * w3;
            }
        }
        const float b2c = b2[lane], gc = ln_g[lane], bbc = ln_b[lane];
        float wr[8];
#pragma unroll
        for (int r = 0; r < 8; ++r) wr[r] = 0.f;
        if (ws_next) {
#pragma unroll
            for (int r = 0; r < 8; ++r) wr[r] = ws_next[r * 64 + lane];
        }
#pragma unroll
        for (int i = 0; i < 4; ++i) {
            int node = base + 4 * w + i;
            float d = acc[i] + b2c;
            float mean = wsum(d) * (1.0f / 64.0f);
            float dd = d - mean;
            float var = wsum(dd * dd) * (1.0f / 64.0f);
            float hv = h[(size_t)node * HIDD + lane] + dd * rsqrtf(var + 1e-5f) * gc + bbc;
            h[(size_t)node * HIDD + lane] = hv;
            if (ws_next) {
                float s0 = wsum(hv * wr[0]), s1 = wsum(hv * wr[1]);
                float s2 = wsum(hv * wr[2]), s3 = wsum(hv * wr[3]);
                float s4 = wsum(hv * wr[4]), s5 = wsum(hv * wr[5]);
                float s6 = wsum(hv * wr[6]), s7 = wsum(hv * wr[7]);
                if (lane == 0) {
                    ((float4*)a_s)[node] = make_float4(s0, s1, s2, s3);
                    ((float4*)a_d)[node] = make_float4(s4, s5, s6, s7);
                }
            }
        }
    }
}

__global__ void copy_out(const float* __restrict__ h, float* __restrict__ out) {
    int i = blockIdx.x * blockDim.x + threadIdx.x;
    if (i < NN * HIDD / 4) ((float4*)out)[i] = ((const float4*)h)[i];
}

extern "C" void kernel_launch(void* const* d_in, const int* in_sizes, int n_in,
                              void* d_out, int out_size, void* d_ws, size_t ws_size,
                              hipStream_t stream) {
    const float* x       = (const float*)d_in[0];
    const int*   ei      = (const int*)d_in[1];
    const float* We      = (const float*)d_in[2];
    const float* be      = (const float*)d_in[3];
    const float* Wc      = (const float*)d_in[4];
    const float* att_src = (const float*)d_in[5];
    const float* att_dst = (const float*)d_in[6];
    const float* bc      = (const float*)d_in[7];
    const float* W1      = (const float*)d_in[8];
    const float* b1      = (const float*)d_in[9];
    const float* W2      = (const float*)d_in[10];
    const float* b2      = (const float*)d_in[11];
    const float* ln_g    = (const float*)d_in[12];
    const float* ln_b    = (const float*)d_in[13];

    char* ws = (char*)d_ws;
    size_t off = 0;
    auto alloc = [&](size_t bytes) -> void* {
        void* p = ws + off; off += (bytes + 255) & ~(size_t)255; return p;
    };
    float* h       = (float*)alloc((size_t)NN * HIDD * 4);
    float* hagg    = (float*)alloc((size_t)NN * HC * 4);
    float* a_s     = (float*)alloc((size_t)NN * NH * 4);
    float* a_d     = (float*)alloc((size_t)NN * NH * 4);
    float* ws_all  = (float*)alloc((size_t)NL * 8 * 64 * 4);
    int*   deg     = (int*)alloc((size_t)NN * 4);
    int*   rowptr  = (int*)alloc((size_t)(NN + 1) * 4);
    int*   cursor  = (int*)alloc((size_t)NN * 4);
    int*   csr_src = (int*)alloc((size_t)(NE + NN) * 4);
    (void)ws_size; (void)in_sizes; (void)n_in; (void)out_size;

    ws_kernel<<<8, 256, 0, stream>>>(Wc, att_src, att_dst, ws_all);
    init_deg<<<(NN + 255) / 256, 256, 0, stream>>>(deg, cursor);
    embed_kernel<<<NN / 16, 256, 0, stream>>>(x, We, be, ws_all, h, a_s, a_d);
    count_edges<<<(NE + 255) / 256, 256, 0, stream>>>(ei, deg);
    scan_kernel<<<1, 1024, 0, stream>>>(deg, rowptr);
    scatter_edges<<<(NE + NN + 255) / 256, 256, 0, stream>>>(ei, rowptr, cursor, csr_src);

    for (int l = 0; l < NL; ++l) {
        agg_kernel<<<NN / 8, 256, 0, stream>>>(h, a_s, a_d, rowptr, csr_src, hagg);
        ffn_kernel<<<NN / 16, 256, 0, stream>>>(hagg,
            Wc + (size_t)l * HIDD * HC, bc + (size_t)l * HC,
            W1 + (size_t)l * HC * DFFD, b1 + (size_t)l * DFFD,
            W2 + (size_t)l * DFFD * HIDD, b2 + (size_t)l * HIDD,
            ln_g + (size_t)l * HIDD, ln_b + (size_t)l * HIDD,
            (l + 1 < NL) ? (ws_all + (size_t)(l + 1) * 8 * 64) : (const float*)nullptr,
            h, a_s, a_d);
    }
    copy_out<<<(NN * HIDD / 4 + 255) / 256, 256, 0, stream>>>(h, (float*)d_out);
}

// Round 6
// 570.831 us; speedup vs baseline: 2.9804x; 1.0385x over previous
//
#include <hip/hip_runtime.h>
#include <cmath>

#define NN   20000   // nodes
#define NE   320000  // edges (before self-loops)
#define IND  256
#define HIDD 64
#define NH   4
#define CD   64
#define HC   256     // NH*CD
#define DFFD 128
#define NL   4
#define NPB  32      // nodes per ffn block

// All float tensors are float32 (verified R1 vs R2). Output f32.

static __device__ __forceinline__ float lrelu(float v) { return v > 0.f ? v : 0.2f * v; }
static __device__ __forceinline__ float wsum(float v) { for (int k = 32; k; k >>= 1) v += __shfl_xor(v, k); return v; }
static __device__ __forceinline__ float wmax(float v) { for (int k = 32; k; k >>= 1) v = fmaxf(v, __shfl_xor(v, k)); return v; }

// ---- ws_all[l][r][k]: r=0..3 -> Wc_head@att_src, r=4..7 -> Wc_head@att_dst ----
__global__ void ws_kernel(const float* __restrict__ Wc, const float* __restrict__ att_src,
                          const float* __restrict__ att_dst, float* __restrict__ ws_all) {
    int idx = blockIdx.x * 256 + threadIdx.x;   // 0..2047 = L*8*64
    int l = idx >> 9, r = (idx >> 6) & 7, k = idx & 63;
    int hh = r & 3;
    const float* att = ((r & 4) ? att_dst : att_src) + (size_t)l * NH * CD + hh * CD;
    const float* wrow = Wc + (size_t)l * HIDD * HC + (size_t)k * HC + hh * CD;
    float s = 0.f;
    for (int c = 0; c < CD; ++c) s += wrow[c] * att[c];
    ws_all[idx] = s;
}

// ---- embed: h = (x @ We + be) * 8, fused layer-0 attention dots; 16 nodes/block ----
__global__ __launch_bounds__(256) void embed_kernel(const float* __restrict__ x,
                                                    const float* __restrict__ We,
                                                    const float* __restrict__ be,
                                                    const float* __restrict__ ws_all,
                                                    float* __restrict__ h,
                                                    float* __restrict__ a_s, float* __restrict__ a_d) {
    __shared__ float s_x[16 * IND];   // 16KB
    const int base = blockIdx.x * 16, t = threadIdx.x;
    for (int idx = t; idx < 16 * IND / 4; idx += 256)
        ((float4*)s_x)[idx] = ((const float4*)(x + (size_t)base * IND))[idx];
    __syncthreads();
    const int c = t & 63, g = t >> 6;   // wave g: nodes 4g..4g+3, lane = channel c
    float acc[4] = {0.f, 0.f, 0.f, 0.f};
    const float4* sx4 = (const float4*)s_x;
#pragma unroll 2
    for (int k4 = 0; k4 < IND / 4; ++k4) {
        float w0 = We[(4 * k4 + 0) * HIDD + c];
        float w1 = We[(4 * k4 + 1) * HIDD + c];
        float w2 = We[(4 * k4 + 2) * HIDD + c];
        float w3 = We[(4 * k4 + 3) * HIDD + c];
#pragma unroll
        for (int i = 0; i < 4; ++i) {
            float4 v = sx4[(4 * g + i) * (IND / 4) + k4];
            acc[i] += v.x * w0 + v.y * w1 + v.z * w2 + v.w * w3;
        }
    }
    float bias = be[c];
    float wr[8];
#pragma unroll
    for (int r = 0; r < 8; ++r) wr[r] = ws_all[r * 64 + c];   // layer 0
#pragma unroll
    for (int i = 0; i < 4; ++i) {
        int node = base + 4 * g + i;
        float hv = (acc[i] + bias) * 8.0f;
        h[(size_t)node * HIDD + c] = hv;
        float s0 = wsum(hv * wr[0]), s1 = wsum(hv * wr[1]);
        float s2 = wsum(hv * wr[2]), s3 = wsum(hv * wr[3]);
        float s4 = wsum(hv * wr[4]), s5 = wsum(hv * wr[5]);
        float s6 = wsum(hv * wr[6]), s7 = wsum(hv * wr[7]);
        if (c == 0) {
            ((float4*)a_s)[node] = make_float4(s0, s1, s2, s3);
            ((float4*)a_d)[node] = make_float4(s4, s5, s6, s7);
        }
    }
}

// ---------------- CSR build ----------------
__global__ void init_deg(int* __restrict__ deg, int* __restrict__ cursor) {
    int i = blockIdx.x * blockDim.x + threadIdx.x;
    if (i < NN) { deg[i] = 1; cursor[i] = 0; }   // self-loop
}

__global__ void count_edges(const int* __restrict__ ei, int* __restrict__ deg) {
    int e = blockIdx.x * blockDim.x + threadIdx.x;
    if (e < NE) atomicAdd(&deg[ei[NE + e]], 1);
}

__global__ void scan_kernel(const int* __restrict__ deg, int* __restrict__ rowptr) {
    __shared__ int part[1024];
    const int t = threadIdx.x;
    const int CH = (NN + 1023) / 1024;
    int lo = t * CH, hi = lo + CH; if (hi > NN) hi = NN;
    int s = 0;
    for (int i = lo; i < hi; ++i) s += deg[i];
    part[t] = s;
    __syncthreads();
    for (int off = 1; off < 1024; off <<= 1) {
        int v = 0;
        if (t >= off) v = part[t - off];
        __syncthreads();
        if (t >= off) part[t] += v;
        __syncthreads();
    }
    int base = (t == 0) ? 0 : part[t - 1];
    for (int i = lo; i < hi; ++i) { rowptr[i] = base; base += deg[i]; }
    if (lo <= NN - 1 && NN - 1 < hi) rowptr[NN] = base;
}

__global__ void scatter_edges(const int* __restrict__ ei, const int* __restrict__ rowptr,
                              int* __restrict__ cursor, int* __restrict__ csr_src) {
    int e = blockIdx.x * blockDim.x + threadIdx.x;
    if (e < NE) {
        int s = ei[e], d = ei[NE + e];
        int pos = atomicAdd(&cursor[d], 1);
        csr_src[rowptr[d] + pos] = s;
    } else if (e < NE + NN) {
        int i = e - NE;
        int pos = atomicAdd(&cursor[i], 1);
        csr_src[rowptr[i] + pos] = i;
    }
}

// ---- agg: one WAVE per node; 8 nodes/block; 4-deep MLP in the gather loop ----
__global__ __launch_bounds__(256) void agg_kernel(
    const float* __restrict__ h, const float* __restrict__ a_s, const float* __restrict__ a_d,
    const int* __restrict__ rowptr, const int* __restrict__ csr_src,
    float* __restrict__ hagg) {
    __shared__ int    s_src[8][64];
    __shared__ float4 s_w[8][64];
    const int t = threadIdx.x, wave = t >> 6, lane = t & 63;
    const float4* as4 = (const float4*)a_s;
#pragma unroll
    for (int nd = 0; nd < 2; ++nd) {
        const int slot = wave * 2 + nd;
        const int i = blockIdx.x * 8 + slot;
        const int lo = rowptr[i], n = rowptr[i + 1] - lo;
        const float4 ad = ((const float4*)a_d)[i];
        float acc0 = 0.f, acc1 = 0.f, acc2 = 0.f, acc3 = 0.f;
        if (n <= 64) {
            float e0 = -1e30f, e1 = -1e30f, e2 = -1e30f, e3 = -1e30f;
            if (lane < n) {
                int s = csr_src[lo + lane];
                s_src[slot][lane] = s;
                float4 a = as4[s];
                e0 = lrelu(a.x + ad.x); e1 = lrelu(a.y + ad.y);
                e2 = lrelu(a.z + ad.z); e3 = lrelu(a.w + ad.w);
            }
            float M0 = wmax(e0), M1 = wmax(e1), M2 = wmax(e2), M3 = wmax(e3);
            float p0 = __expf(e0 - M0), p1 = __expf(e1 - M1);
            float p2 = __expf(e2 - M2), p3 = __expf(e3 - M3);
            float iz0 = 1.f / (wsum(p0) + 1e-16f), iz1 = 1.f / (wsum(p1) + 1e-16f);
            float iz2 = 1.f / (wsum(p2) + 1e-16f), iz3 = 1.f / (wsum(p3) + 1e-16f);
            if (lane < n) s_w[slot][lane] = make_float4(p0 * iz0, p1 * iz1, p2 * iz2, p3 * iz3);
            int j = 0;
            for (; j + 4 <= n; j += 4) {   // 4 independent h-row loads in flight
                int  q0 = s_src[slot][j],     q1 = s_src[slot][j + 1];
                int  q2 = s_src[slot][j + 2], q3 = s_src[slot][j + 3];
                float h0 = h[(size_t)q0 * HIDD + lane], h1 = h[(size_t)q1 * HIDD + lane];
                float h2 = h[(size_t)q2 * HIDD + lane], h3 = h[(size_t)q3 * HIDD + lane];
                float4 w0 = s_w[slot][j],     w1 = s_w[slot][j + 1];
                float4 w2 = s_w[slot][j + 2], w3 = s_w[slot][j + 3];
                acc0 += h0 * w0.x + h1 * w1.x + h2 * w2.x + h3 * w3.x;
                acc1 += h0 * w0.y + h1 * w1.y + h2 * w2.y + h3 * w3.y;
                acc2 += h0 * w0.z + h1 * w1.z + h2 * w2.z + h3 * w3.z;
                acc3 += h0 * w0.w + h1 * w1.w + h2 * w2.w + h3 * w3.w;
            }
            for (; j < n; ++j) {
                float hv = h[(size_t)s_src[slot][j] * HIDD + lane];
                float4 w = s_w[slot][j];
                acc0 += hv * w.x; acc1 += hv * w.y; acc2 += hv * w.z; acc3 += hv * w.w;
            }
        } else {
            float m0 = -1e30f, m1 = -1e30f, m2 = -1e30f, m3 = -1e30f;
            for (int j = lane; j < n; j += 64) {
                int s = csr_src[lo + j];
                float4 a = as4[s];
                m0 = fmaxf(m0, lrelu(a.x + ad.x)); m1 = fmaxf(m1, lrelu(a.y + ad.y));
                m2 = fmaxf(m2, lrelu(a.z + ad.z)); m3 = fmaxf(m3, lrelu(a.w + ad.w));
            }
            m0 = wmax(m0); m1 = wmax(m1); m2 = wmax(m2); m3 = wmax(m3);
            float z0 = 0.f, z1 = 0.f, z2 = 0.f, z3 = 0.f;
            for (int j = lane; j < n; j += 64) {
                int s = csr_src[lo + j];
                float4 a = as4[s];
                z0 += __expf(lrelu(a.x + ad.x) - m0); z1 += __expf(lrelu(a.y + ad.y) - m1);
                z2 += __expf(lrelu(a.z + ad.z) - m2); z3 += __expf(lrelu(a.w + ad.w) - m3);
            }
            float iz0 = 1.f / (wsum(z0) + 1e-16f), iz1 = 1.f / (wsum(z1) + 1e-16f);
            float iz2 = 1.f / (wsum(z2) + 1e-16f), iz3 = 1.f / (wsum(z3) + 1e-16f);
            for (int cb = 0; cb < n; cb += 64) {
                int nn = n - cb; if (nn > 64) nn = 64;
                if (lane < nn) {
                    int s = csr_src[lo + cb + lane];
                    s_src[slot][lane] = s;
                    float4 a = as4[s];
                    s_w[slot][lane] = make_float4(__expf(lrelu(a.x + ad.x) - m0) * iz0,
                                                  __expf(lrelu(a.y + ad.y) - m1) * iz1,
                                                  __expf(lrelu(a.z + ad.z) - m2) * iz2,
                                                  __expf(lrelu(a.w + ad.w) - m3) * iz3);
                }
                int j = 0;
                for (; j + 4 <= nn; j += 4) {
                    int  q0 = s_src[slot][j],     q1 = s_src[slot][j + 1];
                    int  q2 = s_src[slot][j + 2], q3 = s_src[slot][j + 3];
                    float h0 = h[(size_t)q0 * HIDD + lane], h1 = h[(size_t)q1 * HIDD + lane];
                    float h2 = h[(size_t)q2 * HIDD + lane], h3 = h[(size_t)q3 * HIDD + lane];
                    float4 w0 = s_w[slot][j],     w1 = s_w[slot][j + 1];
                    float4 w2 = s_w[slot][j + 2], w3 = s_w[slot][j + 3];
                    acc0 += h0 * w0.x + h1 * w1.x + h2 * w2.x + h3 * w3.x;
                    acc1 += h0 * w0.y + h1 * w1.y + h2 * w2.y + h3 * w3.y;
                    acc2 += h0 * w0.z + h1 * w1.z + h2 * w2.z + h3 * w3.z;
                    acc3 += h0 * w0.w + h1 * w1.w + h2 * w2.w + h3 * w3.w;
                }
                for (; j < nn; ++j) {
                    float hv = h[(size_t)s_src[slot][j] * HIDD + lane];
                    float4 w = s_w[slot][j];
                    acc0 += hv * w.x; acc1 += hv * w.y; acc2 += hv * w.z; acc3 += hv * w.w;
                }
            }
        }
        float* hg = hagg + (size_t)i * HC;
        hg[0 * 64 + lane] = acc0; hg[1 * 64 + lane] = acc1;
        hg[2 * 64 + lane] = acc2; hg[3 * 64 + lane] = acc3;
    }
}

// ---- ffn v2: 32 nodes/block, register-tiled 4x4 outer products ----
// LDS: s_A 32KB (hagg swizzled -> W1 k-tiles -> mid), s_B 32KB (s_in). 64KB -> 2 blk/CU.
__global__ __launch_bounds__(256, 2) void ffn_kernel(
    const float* __restrict__ hagg, const float* __restrict__ Wc, const float* __restrict__ bc,
    const float* __restrict__ W1, const float* __restrict__ b1,
    const float* __restrict__ W2, const float* __restrict__ b2,
    const float* __restrict__ ln_g, const float* __restrict__ ln_b,
    const float* __restrict__ ws_next,
    float* __restrict__ h, float* __restrict__ a_s, float* __restrict__ a_d) {
    __shared__ float s_A[8192];   // 32KB
    __shared__ float s_B[8192];   // 32KB
    float4* sA4 = (float4*)s_A;
    float4* sB4 = (float4*)s_B;
    const int base = blockIdx.x * NPB, t = threadIdx.x;

    // stage hagg (32 nodes x 256) into s_A with per-head k-swizzle:
    // slot(n,hh,k4) = n*64 + hh*16 + ((k4 + 4*hh)&15)  [float4 units]
    {
        const float4* gsrc = (const float4*)(hagg + (size_t)base * HC);
        for (int idx = t; idx < 2048; idx += 256) {
            int n = idx >> 6, rem = idx & 63, hh = rem >> 4, k4 = rem & 15;
            sA4[n * 64 + hh * 16 + ((k4 + 4 * hh) & 15)] = gsrc[idx];
        }
    }
    __syncthreads();

    // GEMM0: s_in[n][c] = sum_k hagg[n][(c>>6)*64+k] * Wc[k][c] + bc[c]
    // thread: cg = t&63 -> channels 4cg..4cg+3 (head hh = cg>>4), wave ng -> nodes 8ng..8ng+7
    {
        const int cg = t & 63, ng = t >> 6, hh = cg >> 4;
        float4 acc[8];
#pragma unroll
        for (int i = 0; i < 8; ++i) acc[i] = make_float4(0.f, 0.f, 0.f, 0.f);
        const float* wbase = Wc + 4 * cg;
#pragma unroll 2
        for (int k4 = 0; k4 < 16; ++k4) {
            float4 w0 = *(const float4*)(wbase + (size_t)(4 * k4 + 0) * HC);
            float4 w1 = *(const float4*)(wbase + (size_t)(4 * k4 + 1) * HC);
            float4 w2 = *(const float4*)(wbase + (size_t)(4 * k4 + 2) * HC);
            float4 w3 = *(const float4*)(wbase + (size_t)(4 * k4 + 3) * HC);
            const int koff = hh * 16 + ((k4 + 4 * hh) & 15);
#pragma unroll
            for (int i = 0; i < 8; ++i) {
                float4 v = sA4[(8 * ng + i) * 64 + koff];   // 4 addrs, 2-way banks: free
                acc[i].x += v.x * w0.x + v.y * w1.x + v.z * w2.x + v.w * w3.x;
                acc[i].y += v.x * w0.y + v.y * w1.y + v.z * w2.y + v.w * w3.y;
                acc[i].z += v.x * w0.z + v.y * w1.z + v.z * w2.z + v.w * w3.z;
                acc[i].w += v.x * w0.w + v.y * w1.w + v.z * w2.w + v.w * w3.w;
            }
        }
        float4 bb = *(const float4*)(bc + 4 * cg);
#pragma unroll
        for (int i = 0; i < 8; ++i)
            sB4[(8 * ng + i) * 64 + cg] = make_float4(acc[i].x + bb.x, acc[i].y + bb.y,
                                                      acc[i].z + bb.z, acc[i].w + bb.w);
    }
    __syncthreads();   // GEMM0 s_A reads done; s_B (s_in) visible

    // GEMM1: mid = gelu(in @ W1 + b1); W1 staged in 4 LDS k-tiles of 64x128 (32KB)
    // thread: fg = t&31 -> channels 4fg..4fg+3, ng2 = t>>5 -> nodes 4ng2..4ng2+3
    const int fg = t & 31, ng2 = t >> 5;
    float4 acc1[4];
#pragma unroll
    for (int i = 0; i < 4; ++i) acc1[i] = make_float4(0.f, 0.f, 0.f, 0.f);
    for (int kt = 0; kt < 4; ++kt) {
        {
            const float4* gsrc = (const float4*)(W1 + (size_t)kt * 64 * DFFD);
            for (int idx = t; idx < 2048; idx += 256) sA4[idx] = gsrc[idx];
        }
        __syncthreads();
#pragma unroll 4
        for (int k4 = 0; k4 < 16; ++k4) {
            float4 wt0 = sA4[(4 * k4 + 0) * 32 + fg];   // W1[k][4fg..4fg+3]
            float4 wt1 = sA4[(4 * k4 + 1) * 32 + fg];
            float4 wt2 = sA4[(4 * k4 + 2) * 32 + fg];
            float4 wt3 = sA4[(4 * k4 + 3) * 32 + fg];
#pragma unroll
            for (int i = 0; i < 4; ++i) {
                float4 v = sB4[(4 * ng2 + i) * 64 + kt * 16 + k4];   // 2 addrs/wave
                acc1[i].x += v.x * wt0.x + v.y * wt1.x + v.z * wt2.x + v.w * wt3.x;
                acc1[i].y += v.x * wt0.y + v.y * wt1.y + v.z * wt2.y + v.w * wt3.y;
                acc1[i].z += v.x * wt0.z + v.y * wt1.z + v.z * wt2.z + v.w * wt3.z;
                acc1[i].w += v.x * wt0.w + v.y * wt1.w + v.z * wt2.w + v.w * wt3.w;
            }
        }
        __syncthreads();   // tile consumed before next stage overwrites s_A
    }
    // gelu -> s_mid in s_A (first 16KB): s_mid4[n*32 + fg]
    {
        float4 bb = *(const float4*)(b1 + 4 * fg);
#pragma unroll
        for (int i = 0; i < 4; ++i) {
            float dx = acc1[i].x + bb.x, dy = acc1[i].y + bb.y;
            float dz = acc1[i].z + bb.z, dw = acc1[i].w + bb.w;
            sA4[(4 * ng2 + i) * 32 + fg] = make_float4(
                0.5f * dx * (1.f + erff(dx * 0.70710678118654752f)),
                0.5f * dy * (1.f + erff(dy * 0.70710678118654752f)),
                0.5f * dz * (1.f + erff(dz * 0.70710678118654752f)),
                0.5f * dw * (1.f + erff(dw * 0.70710678118654752f)));
        }
    }
    __syncthreads();

    // GEMM2 + LN + residual + next-layer attdots; wave w -> nodes 8w..8w+7, lane = channel
    {
        const int lane = t & 63, w = t >> 6;
        float acc2[8];
#pragma unroll
        for (int i = 0; i < 8; ++i) acc2[i] = 0.f;
#pragma unroll 2
        for (int k4 = 0; k4 < 32; ++k4) {
            float w0 = W2[(4 * k4 + 0) * HIDD + lane];
            float w1 = W2[(4 * k4 + 1) * HIDD + lane];
            float w2 = W2[(4 * k4 + 2) * HIDD + lane];
            float w3 = W2[(4 * k4 + 3) * HIDD + lane];
#pragma unroll
            for (int i = 0; i < 8; ++i) {
                float4 v = sA4[(8 * w + i) * 32 + k4];   // wave-uniform broadcast
                acc2[i] += v.x * w0 + v.y * w1 + v.z * w2 + v.w * w3;
            }
        }
        const float b2c = b2[lane], gc = ln_g[lane], bbc = ln_b[lane];
        float wr[8];
#pragma unroll
        for (int r = 0; r < 8; ++r) wr[r] = 0.f;
        if (ws_next) {
#pragma unroll
            for (int r = 0; r < 8; ++r) wr[r] = ws_next[r * 64 + lane];
        }
#pragma unroll
        for (int i = 0; i < 8; ++i) {
            int node = base + 8 * w + i;
            float d = acc2[i] + b2c;
            float mean = wsum(d) * (1.0f / 64.0f);
            float dd = d - mean;
            float var = wsum(dd * dd) * (1.0f / 64.0f);
            float hv = h[(size_t)node * HIDD + lane] + dd * rsqrtf(var + 1e-5f) * gc + bbc;
            h[(size_t)node * HIDD + lane] = hv;
            if (ws_next) {
                float s0 = wsum(hv * wr[0]), s1 = wsum(hv * wr[1]);
                float s2 = wsum(hv * wr[2]), s3 = wsum(hv * wr[3]);
                float s4 = wsum(hv * wr[4]), s5 = wsum(hv * wr[5]);
                float s6 = wsum(hv * wr[6]), s7 = wsum(hv * wr[7]);
                if (lane == 0) {
                    ((float4*)a_s)[node] = make_float4(s0, s1, s2, s3);
                    ((float4*)a_d)[node] = make_float4(s4, s5, s6, s7);
                }
            }
        }
    }
}

__global__ void copy_out(const float* __restrict__ h, float* __restrict__ out) {
    int i = blockIdx.x * blockDim.x + threadIdx.x;
    if (i < NN * HIDD / 4) ((float4*)out)[i] = ((const float4*)h)[i];
}

extern "C" void kernel_launch(void* const* d_in, const int* in_sizes, int n_in,
                              void* d_out, int out_size, void* d_ws, size_t ws_size,
                              hipStream_t stream) {
    const float* x       = (const float*)d_in[0];
    const int*   ei      = (const int*)d_in[1];
    const float* We      = (const float*)d_in[2];
    const float* be      = (const float*)d_in[3];
    const float* Wc      = (const float*)d_in[4];
    const float* att_src = (const float*)d_in[5];
    const float* att_dst = (const float*)d_in[6];
    const float* bc      = (const float*)d_in[7];
    const float* W1      = (const float*)d_in[8];
    const float* b1      = (const float*)d_in[9];
    const float* W2      = (const float*)d_in[10];
    const float* b2      = (const float*)d_in[11];
    const float* ln_g    = (const float*)d_in[12];
    const float* ln_b    = (const float*)d_in[13];

    char* ws = (char*)d_ws;
    size_t off = 0;
    auto alloc = [&](size_t bytes) -> void* {
        void* p = ws + off; off += (bytes + 255) & ~(size_t)255; return p;
    };
    float* h       = (float*)alloc((size_t)NN * HIDD * 4);
    float* hagg    = (float*)alloc((size_t)NN * HC * 4);
    float* a_s     = (float*)alloc((size_t)NN * NH * 4);
    float* a_d     = (float*)alloc((size_t)NN * NH * 4);
    float* ws_all  = (float*)alloc((size_t)NL * 8 * 64 * 4);
    int*   deg     = (int*)alloc((size_t)NN * 4);
    int*   rowptr  = (int*)alloc((size_t)(NN + 1) * 4);
    int*   cursor  = (int*)alloc((size_t)NN * 4);
    int*   csr_src = (int*)alloc((size_t)(NE + NN) * 4);
    (void)ws_size; (void)in_sizes; (void)n_in; (void)out_size;

    ws_kernel<<<8, 256, 0, stream>>>(Wc, att_src, att_dst, ws_all);
    init_deg<<<(NN + 255) / 256, 256, 0, stream>>>(deg, cursor);
    embed_kernel<<<NN / 16, 256, 0, stream>>>(x, We, be, ws_all, h, a_s, a_d);
    count_edges<<<(NE + 255) / 256, 256, 0, stream>>>(ei, deg);
    scan_kernel<<<1, 1024, 0, stream>>>(deg, rowptr);
    scatter_edges<<<(NE + NN + 255) / 256, 256, 0, stream>>>(ei, rowptr, cursor, csr_src);

    for (int l = 0; l < NL; ++l) {
        agg_kernel<<<NN / 8, 256, 0, stream>>>(h, a_s, a_d, rowptr, csr_src, hagg);
        ffn_kernel<<<NN / NPB, 256, 0, stream>>>(hagg,
            Wc + (size_t)l * HIDD * HC, bc + (size_t)l * HC,
            W1 + (size_t)l * HC * DFFD, b1 + (size_t)l * DFFD,
            W2 + (size_t)l * DFFD * HIDD, b2 + (size_t)l * HIDD,
            ln_g + (size_t)l * HIDD, ln_b + (size_t)l * HIDD,
            (l + 1 < NL) ? (ws_all + (size_t)(l + 1) * 8 * 64) : (const float*)nullptr,
            h, a_s, a_d);
    }
    copy_out<<<(NN * HIDD / 4 + 255) / 256, 256, 0, stream>>>(h, (float*)d_out);
}

// Round 7
// 565.631 us; speedup vs baseline: 3.0078x; 1.0092x over previous
//
#include <hip/hip_runtime.h>
#include <cmath>

#define NN   20000   // nodes
#define NE   320000  // edges (before self-loops)
#define IND  256
#define HIDD 64
#define NH   4
#define CD   64
#define HC   256     // NH*CD
#define DFFD 128
#define NL   4

// All float tensors are float32 (verified R1 vs R2). Output f32.
// R6 lesson: keep ffn at >=3 blocks/CU; occupancy beats LDS-op reduction here.

static __device__ __forceinline__ float lrelu(float v) { return v > 0.f ? v : 0.2f * v; }
static __device__ __forceinline__ float wsum(float v) { for (int k = 32; k; k >>= 1) v += __shfl_xor(v, k); return v; }
static __device__ __forceinline__ float wmax(float v) { for (int k = 32; k; k >>= 1) v = fmaxf(v, __shfl_xor(v, k)); return v; }

// ---- ws_all[l][r][k]: r=0..3 -> Wc_head@att_src, r=4..7 -> Wc_head@att_dst ----
__global__ void ws_kernel(const float* __restrict__ Wc, const float* __restrict__ att_src,
                          const float* __restrict__ att_dst, float* __restrict__ ws_all) {
    int idx = blockIdx.x * 256 + threadIdx.x;   // 0..2047 = L*8*64
    int l = idx >> 9, r = (idx >> 6) & 7, k = idx & 63;
    int hh = r & 3;
    const float* att = ((r & 4) ? att_dst : att_src) + (size_t)l * NH * CD + hh * CD;
    const float* wrow = Wc + (size_t)l * HIDD * HC + (size_t)k * HC + hh * CD;
    float s = 0.f;
    for (int c = 0; c < CD; ++c) s += wrow[c] * att[c];
    ws_all[idx] = s;
}

// ---- W1eff[l][h*64+k][f] = sum_c Wc[l][k][h*64+c] * W1[l][h*64+c][f] ----
// Folds the per-head out-projection (GEMM0) into W1: one block per (l,hk) row.
__global__ void w1eff_kernel(const float* __restrict__ Wc, const float* __restrict__ W1,
                             float* __restrict__ W1eff) {
    const int b = blockIdx.x;               // 0..NL*256-1
    const int l = b >> 8, hk = b & 255, hh = hk >> 6, kl = hk & 63;
    const int f = threadIdx.x;              // 0..127
    const float* wc = Wc + (size_t)l * HIDD * HC + (size_t)kl * HC + hh * 64;
    const float* w1 = W1 + (size_t)l * HC * DFFD + (size_t)(hh * 64) * DFFD + f;
    float s = 0.f;
#pragma unroll 4
    for (int c = 0; c < 64; ++c) s += wc[c] * w1[(size_t)c * DFFD];
    W1eff[(size_t)l * HC * DFFD + (size_t)hk * DFFD + f] = s;
}

// ---- b1eff[l][f] = b1[l][f] + sum_c bc[l][c] * W1[l][c][f] ----
__global__ void b1eff_kernel(const float* __restrict__ bc, const float* __restrict__ W1,
                             const float* __restrict__ b1, float* __restrict__ b1eff) {
    const int l = blockIdx.x, f = threadIdx.x;   // NL blocks x 128 threads
    const float* w1 = W1 + (size_t)l * HC * DFFD + f;
    const float* bcl = bc + (size_t)l * HC;
    float s = b1[(size_t)l * DFFD + f];
    for (int c = 0; c < HC; ++c) s += bcl[c] * w1[(size_t)c * DFFD];
    b1eff[l * DFFD + f] = s;
}

// ---- embed: h = (x @ We + be) * 8, fused layer-0 attention dots; 16 nodes/block ----
__global__ __launch_bounds__(256) void embed_kernel(const float* __restrict__ x,
                                                    const float* __restrict__ We,
                                                    const float* __restrict__ be,
                                                    const float* __restrict__ ws_all,
                                                    float* __restrict__ h,
                                                    float* __restrict__ a_s, float* __restrict__ a_d) {
    __shared__ float s_x[16 * IND];   // 16KB
    const int base = blockIdx.x * 16, t = threadIdx.x;
    for (int idx = t; idx < 16 * IND / 4; idx += 256)
        ((float4*)s_x)[idx] = ((const float4*)(x + (size_t)base * IND))[idx];
    __syncthreads();
    const int c = t & 63, g = t >> 6;   // wave g: nodes 4g..4g+3, lane = channel c
    float acc[4] = {0.f, 0.f, 0.f, 0.f};
    const float4* sx4 = (const float4*)s_x;
#pragma unroll 2
    for (int k4 = 0; k4 < IND / 4; ++k4) {
        float w0 = We[(4 * k4 + 0) * HIDD + c];
        float w1 = We[(4 * k4 + 1) * HIDD + c];
        float w2 = We[(4 * k4 + 2) * HIDD + c];
        float w3 = We[(4 * k4 + 3) * HIDD + c];
#pragma unroll
        for (int i = 0; i < 4; ++i) {
            float4 v = sx4[(4 * g + i) * (IND / 4) + k4];
            acc[i] += v.x * w0 + v.y * w1 + v.z * w2 + v.w * w3;
        }
    }
    float bias = be[c];
    float wr[8];
#pragma unroll
    for (int r = 0; r < 8; ++r) wr[r] = ws_all[r * 64 + c];   // layer 0
#pragma unroll
    for (int i = 0; i < 4; ++i) {
        int node = base + 4 * g + i;
        float hv = (acc[i] + bias) * 8.0f;
        h[(size_t)node * HIDD + c] = hv;
        float s0 = wsum(hv * wr[0]), s1 = wsum(hv * wr[1]);
        float s2 = wsum(hv * wr[2]), s3 = wsum(hv * wr[3]);
        float s4 = wsum(hv * wr[4]), s5 = wsum(hv * wr[5]);
        float s6 = wsum(hv * wr[6]), s7 = wsum(hv * wr[7]);
        if (c == 0) {
            ((float4*)a_s)[node] = make_float4(s0, s1, s2, s3);
            ((float4*)a_d)[node] = make_float4(s4, s5, s6, s7);
        }
    }
}

// ---------------- CSR build ----------------
__global__ void init_deg(int* __restrict__ deg, int* __restrict__ cursor) {
    int i = blockIdx.x * blockDim.x + threadIdx.x;
    if (i < NN) { deg[i] = 1; cursor[i] = 0; }   // self-loop
}

__global__ void count_edges(const int* __restrict__ ei, int* __restrict__ deg) {
    int e = blockIdx.x * blockDim.x + threadIdx.x;
    if (e < NE) atomicAdd(&deg[ei[NE + e]], 1);
}

__global__ void scan_kernel(const int* __restrict__ deg, int* __restrict__ rowptr) {
    __shared__ int part[1024];
    const int t = threadIdx.x;
    const int CH = (NN + 1023) / 1024;
    int lo = t * CH, hi = lo + CH; if (hi > NN) hi = NN;
    int s = 0;
    for (int i = lo; i < hi; ++i) s += deg[i];
    part[t] = s;
    __syncthreads();
    for (int off = 1; off < 1024; off <<= 1) {
        int v = 0;
        if (t >= off) v = part[t - off];
        __syncthreads();
        if (t >= off) part[t] += v;
        __syncthreads();
    }
    int base = (t == 0) ? 0 : part[t - 1];
    for (int i = lo; i < hi; ++i) { rowptr[i] = base; base += deg[i]; }
    if (lo <= NN - 1 && NN - 1 < hi) rowptr[NN] = base;
}

__global__ void scatter_edges(const int* __restrict__ ei, const int* __restrict__ rowptr,
                              int* __restrict__ cursor, int* __restrict__ csr_src) {
    int e = blockIdx.x * blockDim.x + threadIdx.x;
    if (e < NE) {
        int s = ei[e], d = ei[NE + e];
        int pos = atomicAdd(&cursor[d], 1);
        csr_src[rowptr[d] + pos] = s;
    } else if (e < NE + NN) {
        int i = e - NE;
        int pos = atomicAdd(&cursor[i], 1);
        csr_src[rowptr[i] + pos] = i;
    }
}

// ---- agg: one WAVE per node; 8 nodes/block; 4-deep MLP in the gather loop ----
__global__ __launch_bounds__(256) void agg_kernel(
    const float* __restrict__ h, const float* __restrict__ a_s, const float* __restrict__ a_d,
    const int* __restrict__ rowptr, const int* __restrict__ csr_src,
    float* __restrict__ hagg) {
    __shared__ int    s_src[8][64];
    __shared__ float4 s_w[8][64];
    const int t = threadIdx.x, wave = t >> 6, lane = t & 63;
    const float4* as4 = (const float4*)a_s;
#pragma unroll
    for (int nd = 0; nd < 2; ++nd) {
        const int slot = wave * 2 + nd;
        const int i = blockIdx.x * 8 + slot;
        const int lo = rowptr[i], n = rowptr[i + 1] - lo;
        const float4 ad = ((const float4*)a_d)[i];
        float acc0 = 0.f, acc1 = 0.f, acc2 = 0.f, acc3 = 0.f;
        if (n <= 64) {
            float e0 = -1e30f, e1 = -1e30f, e2 = -1e30f, e3 = -1e30f;
            if (lane < n) {
                int s = csr_src[lo + lane];
                s_src[slot][lane] = s;
                float4 a = as4[s];
                e0 = lrelu(a.x + ad.x); e1 = lrelu(a.y + ad.y);
                e2 = lrelu(a.z + ad.z); e3 = lrelu(a.w + ad.w);
            }
            float M0 = wmax(e0), M1 = wmax(e1), M2 = wmax(e2), M3 = wmax(e3);
            float p0 = __expf(e0 - M0), p1 = __expf(e1 - M1);
            float p2 = __expf(e2 - M2), p3 = __expf(e3 - M3);
            float iz0 = 1.f / (wsum(p0) + 1e-16f), iz1 = 1.f / (wsum(p1) + 1e-16f);
            float iz2 = 1.f / (wsum(p2) + 1e-16f), iz3 = 1.f / (wsum(p3) + 1e-16f);
            if (lane < n) s_w[slot][lane] = make_float4(p0 * iz0, p1 * iz1, p2 * iz2, p3 * iz3);
            int j = 0;
            for (; j + 4 <= n; j += 4) {   // 4 independent h-row loads in flight
                int  q0 = s_src[slot][j],     q1 = s_src[slot][j + 1];
                int  q2 = s_src[slot][j + 2], q3 = s_src[slot][j + 3];
                float h0 = h[(size_t)q0 * HIDD + lane], h1 = h[(size_t)q1 * HIDD + lane];
                float h2 = h[(size_t)q2 * HIDD + lane], h3 = h[(size_t)q3 * HIDD + lane];
                float4 w0 = s_w[slot][j],     w1 = s_w[slot][j + 1];
                float4 w2 = s_w[slot][j + 2], w3 = s_w[slot][j + 3];
                acc0 += h0 * w0.x + h1 * w1.x + h2 * w2.x + h3 * w3.x;
                acc1 += h0 * w0.y + h1 * w1.y + h2 * w2.y + h3 * w3.y;
                acc2 += h0 * w0.z + h1 * w1.z + h2 * w2.z + h3 * w3.z;
                acc3 += h0 * w0.w + h1 * w1.w + h2 * w2.w + h3 * w3.w;
            }
            for (; j < n; ++j) {
                float hv = h[(size_t)s_src[slot][j] * HIDD + lane];
                float4 w = s_w[slot][j];
                acc0 += hv * w.x; acc1 += hv * w.y; acc2 += hv * w.z; acc3 += hv * w.w;
            }
        } else {
            float m0 = -1e30f, m1 = -1e30f, m2 = -1e30f, m3 = -1e30f;
            for (int j = lane; j < n; j += 64) {
                int s = csr_src[lo + j];
                float4 a = as4[s];
                m0 = fmaxf(m0, lrelu(a.x + ad.x)); m1 = fmaxf(m1, lrelu(a.y + ad.y));
                m2 = fmaxf(m2, lrelu(a.z + ad.z)); m3 = fmaxf(m3, lrelu(a.w + ad.w));
            }
            m0 = wmax(m0); m1 = wmax(m1); m2 = wmax(m2); m3 = wmax(m3);
            float z0 = 0.f, z1 = 0.f, z2 = 0.f, z3 = 0.f;
            for (int j = lane; j < n; j += 64) {
                int s = csr_src[lo + j];
                float4 a = as4[s];
                z0 += __expf(lrelu(a.x + ad.x) - m0); z1 += __expf(lrelu(a.y + ad.y) - m1);
                z2 += __expf(lrelu(a.z + ad.z) - m2); z3 += __expf(lrelu(a.w + ad.w) - m3);
            }
            float iz0 = 1.f / (wsum(z0) + 1e-16f), iz1 = 1.f / (wsum(z1) + 1e-16f);
            float iz2 = 1.f / (wsum(z2) + 1e-16f), iz3 = 1.f / (wsum(z3) + 1e-16f);
            for (int cb = 0; cb < n; cb += 64) {
                int nn = n - cb; if (nn > 64) nn = 64;
                if (lane < nn) {
                    int s = csr_src[lo + cb + lane];
                    s_src[slot][lane] = s;
                    float4 a = as4[s];
                    s_w[slot][lane] = make_float4(__expf(lrelu(a.x + ad.x) - m0) * iz0,
                                                  __expf(lrelu(a.y + ad.y) - m1) * iz1,
                                                  __expf(lrelu(a.z + ad.z) - m2) * iz2,
                                                  __expf(lrelu(a.w + ad.w) - m3) * iz3);
                }
                int j = 0;
                for (; j + 4 <= nn; j += 4) {
                    int  q0 = s_src[slot][j],     q1 = s_src[slot][j + 1];
                    int  q2 = s_src[slot][j + 2], q3 = s_src[slot][j + 3];
                    float h0 = h[(size_t)q0 * HIDD + lane], h1 = h[(size_t)q1 * HIDD + lane];
                    float h2 = h[(size_t)q2 * HIDD + lane], h3 = h[(size_t)q3 * HIDD + lane];
                    float4 w0 = s_w[slot][j],     w1 = s_w[slot][j + 1];
                    float4 w2 = s_w[slot][j + 2], w3 = s_w[slot][j + 3];
                    acc0 += h0 * w0.x + h1 * w1.x + h2 * w2.x + h3 * w3.x;
                    acc1 += h0 * w0.y + h1 * w1.y + h2 * w2.y + h3 * w3.y;
                    acc2 += h0 * w0.z + h1 * w1.z + h2 * w2.z + h3 * w3.z;
                    acc3 += h0 * w0.w + h1 * w1.w + h2 * w2.w + h3 * w3.w;
                }
                for (; j < nn; ++j) {
                    float hv = h[(size_t)s_src[slot][j] * HIDD + lane];
                    float4 w = s_w[slot][j];
                    acc0 += hv * w.x; acc1 += hv * w.y; acc2 += hv * w.z; acc3 += hv * w.w;
                }
            }
        }
        float* hg = hagg + (size_t)i * HC;
        hg[0 * 64 + lane] = acc0; hg[1 * 64 + lane] = acc1;
        hg[2 * 64 + lane] = acc2; hg[3 * 64 + lane] = acc3;
    }
}

// ---- ffn v3: GEMM0 folded into W1eff. mid = gelu(hagg@W1eff + b1eff);
//      f = mid@W2 + b2; h += LN(f); fused next-layer attention dots.
// 16 nodes/block. LDS: s_in 16KB (hagg) + s_buf 32KB (W1eff k-tiles -> mid) = 48KB -> 3 blk/CU.
__global__ __launch_bounds__(256, 3) void ffn_kernel(
    const float* __restrict__ hagg, const float* __restrict__ W1eff, const float* __restrict__ b1eff,
    const float* __restrict__ W2, const float* __restrict__ b2,
    const float* __restrict__ ln_g, const float* __restrict__ ln_b,
    const float* __restrict__ ws_next,
    float* __restrict__ h, float* __restrict__ a_s, float* __restrict__ a_d) {
    __shared__ float s_buf[8192];       // 32KB: W1eff k-tile(32KB) -> mid(8KB)
    __shared__ float s_in[16 * HC];     // 16KB hagg
    const int base = blockIdx.x * 16, t = threadIdx.x;
    for (int idx = t; idx < 16 * HC / 4; idx += 256)
        ((float4*)s_in)[idx] = ((const float4*)(hagg + (size_t)base * HC))[idx];
    // visibility of s_in covered by the first barrier pair inside the kt loop

    // GEMM1: mid = gelu(hagg @ W1eff + b1eff); W1eff staged in 4 LDS k-tiles of 64x128
    // thread: f = t&127, 8 nodes (t>>7)
    const int f = t & 127, g = t >> 7;
    float acc1[8];
#pragma unroll
    for (int i = 0; i < 8; ++i) acc1[i] = 0.f;
    {
        const float4* si4 = (const float4*)s_in;
        for (int kt = 0; kt < 4; ++kt) {
            __syncthreads();   // prior s_buf readers done (previous tile); kt=0: covers s_in stage
            const float4* gsrc = (const float4*)(W1eff + (size_t)kt * 64 * DFFD);
            for (int idx = t; idx < 2048; idx += 256)
                ((float4*)s_buf)[idx] = gsrc[idx];
            __syncthreads();
#pragma unroll 4
            for (int k4 = 0; k4 < 16; ++k4) {
                float w0 = s_buf[(4 * k4 + 0) * DFFD + f];   // bank=f%32: 2-way, free
                float w1 = s_buf[(4 * k4 + 1) * DFFD + f];
                float w2 = s_buf[(4 * k4 + 2) * DFFD + f];
                float w3 = s_buf[(4 * k4 + 3) * DFFD + f];
#pragma unroll
                for (int i = 0; i < 8; ++i) {
                    float4 v = si4[(8 * g + i) * 64 + kt * 16 + k4];   // wave-uniform broadcast
                    acc1[i] += v.x * w0 + v.y * w1 + v.z * w2 + v.w * w3;
                }
            }
        }
        __syncthreads();
        float bb = b1eff[f];
#pragma unroll
        for (int i = 0; i < 8; ++i) {
            float d = acc1[i] + bb;
            s_buf[(8 * g + i) * DFFD + f] = 0.5f * d * (1.f + erff(d * 0.70710678118654752f));
        }
    }
    __syncthreads();

    // GEMM2 + LN + residual + next-layer attdots; wave w -> nodes 4w..4w+3, lane = channel
    {
        const int lane = t & 63, w = t >> 6;
        float acc[4];
#pragma unroll
        for (int i = 0; i < 4; ++i) acc[i] = 0.f;
        const float4* sm4 = (const float4*)s_buf;
#pragma unroll 4
        for (int k4 = 0; k4 < 32; ++k4) {
            float w0 = W2[(4 * k4 + 0) * HIDD + lane];
            float w1 = W2[(4 * k4 + 1) * HIDD + lane];
            float w2 = W2[(4 * k4 + 2) * HIDD + lane];
            float w3 = W2[(4 * k4 + 3) * HIDD + lane];
#pragma unroll
            for (int i = 0; i < 4; ++i) {
                float4 v = sm4[(4 * w + i) * 32 + k4];   // wave-uniform
                acc[i] += v.x * w0 + v.y * w1 + v.z * w2 + v.w * w3;
            }
        }
        const float b2c = b2[lane], gc = ln_g[lane], bbc = ln_b[lane];
        float wr[8];
#pragma unroll
        for (int r = 0; r < 8; ++r) wr[r] = 0.f;
        if (ws_next) {
#pragma unroll
            for (int r = 0; r < 8; ++r) wr[r] = ws_next[r * 64 + lane];
        }
#pragma unroll
        for (int i = 0; i < 4; ++i) {
            int node = base + 4 * w + i;
            float d = acc[i] + b2c;
            float mean = wsum(d) * (1.0f / 64.0f);
            float dd = d - mean;
            float var = wsum(dd * dd) * (1.0f / 64.0f);
            float hv = h[(size_t)node * HIDD + lane] + dd * rsqrtf(var + 1e-5f) * gc + bbc;
            h[(size_t)node * HIDD + lane] = hv;
            if (ws_next) {
                float s0 = wsum(hv * wr[0]), s1 = wsum(hv * wr[1]);
                float s2 = wsum(hv * wr[2]), s3 = wsum(hv * wr[3]);
                float s4 = wsum(hv * wr[4]), s5 = wsum(hv * wr[5]);
                float s6 = wsum(hv * wr[6]), s7 = wsum(hv * wr[7]);
                if (lane == 0) {
                    ((float4*)a_s)[node] = make_float4(s0, s1, s2, s3);
                    ((float4*)a_d)[node] = make_float4(s4, s5, s6, s7);
                }
            }
        }
    }
}

__global__ void copy_out(const float* __restrict__ h, float* __restrict__ out) {
    int i = blockIdx.x * blockDim.x + threadIdx.x;
    if (i < NN * HIDD / 4) ((float4*)out)[i] = ((const float4*)h)[i];
}

extern "C" void kernel_launch(void* const* d_in, const int* in_sizes, int n_in,
                              void* d_out, int out_size, void* d_ws, size_t ws_size,
                              hipStream_t stream) {
    const float* x       = (const float*)d_in[0];
    const int*   ei      = (const int*)d_in[1];
    const float* We      = (const float*)d_in[2];
    const float* be      = (const float*)d_in[3];
    const float* Wc      = (const float*)d_in[4];
    const float* att_src = (const float*)d_in[5];
    const float* att_dst = (const float*)d_in[6];
    const float* bc      = (const float*)d_in[7];
    const float* W1      = (const float*)d_in[8];
    const float* b1      = (const float*)d_in[9];
    const float* W2      = (const float*)d_in[10];
    const float* b2      = (const float*)d_in[11];
    const float* ln_g    = (const float*)d_in[12];
    const float* ln_b    = (const float*)d_in[13];

    char* ws = (char*)d_ws;
    size_t off = 0;
    auto alloc = [&](size_t bytes) -> void* {
        void* p = ws + off; off += (bytes + 255) & ~(size_t)255; return p;
    };
    float* h       = (float*)alloc((size_t)NN * HIDD * 4);
    float* hagg    = (float*)alloc((size_t)NN * HC * 4);
    float* a_s     = (float*)alloc((size_t)NN * NH * 4);
    float* a_d     = (float*)alloc((size_t)NN * NH * 4);
    float* ws_all  = (float*)alloc((size_t)NL * 8 * 64 * 4);
    float* W1eff   = (float*)alloc((size_t)NL * HC * DFFD * 4);
    float* b1eff   = (float*)alloc((size_t)NL * DFFD * 4);
    int*   deg     = (int*)alloc((size_t)NN * 4);
    int*   rowptr  = (int*)alloc((size_t)(NN + 1) * 4);
    int*   cursor  = (int*)alloc((size_t)NN * 4);
    int*   csr_src = (int*)alloc((size_t)(NE + NN) * 4);
    (void)ws_size; (void)in_sizes; (void)n_in; (void)out_size;

    ws_kernel<<<8, 256, 0, stream>>>(Wc, att_src, att_dst, ws_all);
    w1eff_kernel<<<NL * 256, 128, 0, stream>>>(Wc, W1, W1eff);
    b1eff_kernel<<<NL, 128, 0, stream>>>(bc, W1, b1, b1eff);
    init_deg<<<(NN + 255) / 256, 256, 0, stream>>>(deg, cursor);
    embed_kernel<<<NN / 16, 256, 0, stream>>>(x, We, be, ws_all, h, a_s, a_d);
    count_edges<<<(NE + 255) / 256, 256, 0, stream>>>(ei, deg);
    scan_kernel<<<1, 1024, 0, stream>>>(deg, rowptr);
    scatter_edges<<<(NE + NN + 255) / 256, 256, 0, stream>>>(ei, rowptr, cursor, csr_src);

    for (int l = 0; l < NL; ++l) {
        agg_kernel<<<NN / 8, 256, 0, stream>>>(h, a_s, a_d, rowptr, csr_src, hagg);
        ffn_kernel<<<NN / 16, 256, 0, stream>>>(hagg,
            W1eff + (size_t)l * HC * DFFD, b1eff + (size_t)l * DFFD,
            W2 + (size_t)l * DFFD * HIDD, b2 + (size_t)l * HIDD,
            ln_g + (size_t)l * HIDD, ln_b + (size_t)l * HIDD,
            (l + 1 < NL) ? (ws_all + (size_t)(l + 1) * 8 * 64) : (const float*)nullptr,
            h, a_s, a_d);
    }
    copy_out<<<(NN * HIDD / 4 + 255) / 256, 256, 0, stream>>>(h, (float*)d_out);
}

// Round 8
// 509.231 us; speedup vs baseline: 3.3409x; 1.1108x over previous
//
#include <hip/hip_runtime.h>
#include <cmath>

#define NN   20000   // nodes
#define NE   320000  // edges (before self-loops)
#define IND  256
#define HIDD 64
#define NH   4
#define CD   64
#define HC   256     // NH*CD
#define DFFD 128
#define NL   4

// All float tensors are float32 (verified R1 vs R2). Output f32.
// R6 lesson: keep layer kernel at >=3 blocks/CU; occupancy beats LDS-op reduction.
// R7 lesson: profiled dispatch dur is inflated vs graph-replay wall clock; trust totals.

static __device__ __forceinline__ float lrelu(float v) { return v > 0.f ? v : 0.2f * v; }
static __device__ __forceinline__ float wsum(float v) { for (int k = 32; k; k >>= 1) v += __shfl_xor(v, k); return v; }
static __device__ __forceinline__ float wmax(float v) { for (int k = 32; k; k >>= 1) v = fmaxf(v, __shfl_xor(v, k)); return v; }

// ---- ws_all[l][r][k]: r=0..3 -> Wc_head@att_src, r=4..7 -> Wc_head@att_dst ----
__global__ void ws_kernel(const float* __restrict__ Wc, const float* __restrict__ att_src,
                          const float* __restrict__ att_dst, float* __restrict__ ws_all) {
    int idx = blockIdx.x * 256 + threadIdx.x;   // 0..2047 = L*8*64
    int l = idx >> 9, r = (idx >> 6) & 7, k = idx & 63;
    int hh = r & 3;
    const float* att = ((r & 4) ? att_dst : att_src) + (size_t)l * NH * CD + hh * CD;
    const float* wrow = Wc + (size_t)l * HIDD * HC + (size_t)k * HC + hh * CD;
    float s = 0.f;
    for (int c = 0; c < CD; ++c) s += wrow[c] * att[c];
    ws_all[idx] = s;
}

// ---- W1eff[l][h*64+k][f] = sum_c Wc[l][k][h*64+c] * W1[l][h*64+c][f] ----
__global__ void w1eff_kernel(const float* __restrict__ Wc, const float* __restrict__ W1,
                             float* __restrict__ W1eff) {
    const int b = blockIdx.x;               // 0..NL*256-1
    const int l = b >> 8, hk = b & 255, hh = hk >> 6, kl = hk & 63;
    const int f = threadIdx.x;              // 0..127
    const float* wc = Wc + (size_t)l * HIDD * HC + (size_t)kl * HC + hh * 64;
    const float* w1 = W1 + (size_t)l * HC * DFFD + (size_t)(hh * 64) * DFFD + f;
    float s = 0.f;
#pragma unroll 4
    for (int c = 0; c < 64; ++c) s += wc[c] * w1[(size_t)c * DFFD];
    W1eff[(size_t)l * HC * DFFD + (size_t)hk * DFFD + f] = s;
}

// ---- b1eff[l][f] = b1[l][f] + sum_c bc[l][c] * W1[l][c][f] ----
__global__ void b1eff_kernel(const float* __restrict__ bc, const float* __restrict__ W1,
                             const float* __restrict__ b1, float* __restrict__ b1eff) {
    const int l = blockIdx.x, f = threadIdx.x;   // NL blocks x 128 threads
    const float* w1 = W1 + (size_t)l * HC * DFFD + f;
    const float* bcl = bc + (size_t)l * HC;
    float s = b1[(size_t)l * DFFD + f];
    for (int c = 0; c < HC; ++c) s += bcl[c] * w1[(size_t)c * DFFD];
    b1eff[l * DFFD + f] = s;
}

// ---- embed: h = (x @ We + be) * 8, fused layer-0 attention dots; 16 nodes/block ----
__global__ __launch_bounds__(256) void embed_kernel(const float* __restrict__ x,
                                                    const float* __restrict__ We,
                                                    const float* __restrict__ be,
                                                    const float* __restrict__ ws_all,
                                                    float* __restrict__ h,
                                                    float* __restrict__ a_s, float* __restrict__ a_d) {
    __shared__ float s_x[16 * IND];   // 16KB
    const int base = blockIdx.x * 16, t = threadIdx.x;
    for (int idx = t; idx < 16 * IND / 4; idx += 256)
        ((float4*)s_x)[idx] = ((const float4*)(x + (size_t)base * IND))[idx];
    __syncthreads();
    const int c = t & 63, g = t >> 6;   // wave g: nodes 4g..4g+3, lane = channel c
    float acc[4] = {0.f, 0.f, 0.f, 0.f};
    const float4* sx4 = (const float4*)s_x;
#pragma unroll 2
    for (int k4 = 0; k4 < IND / 4; ++k4) {
        float w0 = We[(4 * k4 + 0) * HIDD + c];
        float w1 = We[(4 * k4 + 1) * HIDD + c];
        float w2 = We[(4 * k4 + 2) * HIDD + c];
        float w3 = We[(4 * k4 + 3) * HIDD + c];
#pragma unroll
        for (int i = 0; i < 4; ++i) {
            float4 v = sx4[(4 * g + i) * (IND / 4) + k4];
            acc[i] += v.x * w0 + v.y * w1 + v.z * w2 + v.w * w3;
        }
    }
    float bias = be[c];
    float wr[8];
#pragma unroll
    for (int r = 0; r < 8; ++r) wr[r] = ws_all[r * 64 + c];   // layer 0
#pragma unroll
    for (int i = 0; i < 4; ++i) {
        int node = base + 4 * g + i;
        float hv = (acc[i] + bias) * 8.0f;
        h[(size_t)node * HIDD + c] = hv;
        float s0 = wsum(hv * wr[0]), s1 = wsum(hv * wr[1]);
        float s2 = wsum(hv * wr[2]), s3 = wsum(hv * wr[3]);
        float s4 = wsum(hv * wr[4]), s5 = wsum(hv * wr[5]);
        float s6 = wsum(hv * wr[6]), s7 = wsum(hv * wr[7]);
        if (c == 0) {
            ((float4*)a_s)[node] = make_float4(s0, s1, s2, s3);
            ((float4*)a_d)[node] = make_float4(s4, s5, s6, s7);
        }
    }
}

// ---------------- CSR build ----------------
__global__ void init_deg(int* __restrict__ deg, int* __restrict__ cursor) {
    int i = blockIdx.x * blockDim.x + threadIdx.x;
    if (i < NN) { deg[i] = 1; cursor[i] = 0; }   // self-loop
}

__global__ void count_edges(const int* __restrict__ ei, int* __restrict__ deg) {
    int e = blockIdx.x * blockDim.x + threadIdx.x;
    if (e < NE) atomicAdd(&deg[ei[NE + e]], 1);
}

__global__ void scan_kernel(const int* __restrict__ deg, int* __restrict__ rowptr) {
    __shared__ int part[1024];
    const int t = threadIdx.x;
    const int CH = (NN + 1023) / 1024;
    int lo = t * CH, hi = lo + CH; if (hi > NN) hi = NN;
    int s = 0;
    for (int i = lo; i < hi; ++i) s += deg[i];
    part[t] = s;
    __syncthreads();
    for (int off = 1; off < 1024; off <<= 1) {
        int v = 0;
        if (t >= off) v = part[t - off];
        __syncthreads();
        if (t >= off) part[t] += v;
        __syncthreads();
    }
    int base = (t == 0) ? 0 : part[t - 1];
    for (int i = lo; i < hi; ++i) { rowptr[i] = base; base += deg[i]; }
    if (lo <= NN - 1 && NN - 1 < hi) rowptr[NN] = base;
}

__global__ void scatter_edges(const int* __restrict__ ei, const int* __restrict__ rowptr,
                              int* __restrict__ cursor, int* __restrict__ csr_src) {
    int e = blockIdx.x * blockDim.x + threadIdx.x;
    if (e < NE) {
        int s = ei[e], d = ei[NE + e];
        int pos = atomicAdd(&cursor[d], 1);
        csr_src[rowptr[d] + pos] = s;
    } else if (e < NE + NN) {
        int i = e - NE;
        int pos = atomicAdd(&cursor[i], 1);
        csr_src[rowptr[i] + pos] = i;
    }
}

// ---- fused layer: gather/softmax-aggregate (wave-per-node) -> GEMM1 -> GEMM2+LN+res ----
// 16 nodes/block, 1250 blocks. Ping-pong h/a_s/a_d buffers across layers (race-free).
// LDS: s_in 16KB + s_buf 32KB (gather scratch -> W1eff k-tiles -> mid) = 48KB -> 3 blk/CU.
__global__ __launch_bounds__(256, 3) void layer_kernel(
    const float* __restrict__ h_in, const float* __restrict__ a_s_in, const float* __restrict__ a_d_in,
    const int* __restrict__ rowptr, const int* __restrict__ csr_src,
    const float* __restrict__ W1eff, const float* __restrict__ b1eff,
    const float* __restrict__ W2, const float* __restrict__ b2,
    const float* __restrict__ ln_g, const float* __restrict__ ln_b,
    const float* __restrict__ ws_next,
    float* __restrict__ h_out, float* __restrict__ a_s_out, float* __restrict__ a_d_out) {
    __shared__ float s_in[16 * HC];   // 16KB aggregated node vectors
    __shared__ float s_buf[8192];     // 32KB: gather scratch -> W1eff tile -> mid
    const int base = blockIdx.x * 16, t = threadIdx.x, wave = t >> 6, lane = t & 63;

    // ---- phase 1: softmax-attention aggregation, wave-synchronous, 4 nodes/wave ----
    {
        int*    s_src = (int*)s_buf + wave * 64;             // per-wave [64]
        float4* s_w   = (float4*)(s_buf + 256) + wave * 64;  // per-wave [64]
        const float4* as4 = (const float4*)a_s_in;
        for (int nd = 0; nd < 4; ++nd) {
            const int node = base + wave * 4 + nd;
            const int lo = rowptr[node], n = rowptr[node + 1] - lo;
            const float4 ad = ((const float4*)a_d_in)[node];
            float g0 = 0.f, g1 = 0.f, g2 = 0.f, g3 = 0.f;
            if (n <= 64) {
                float e0 = -1e30f, e1 = -1e30f, e2 = -1e30f, e3 = -1e30f;
                if (lane < n) {
                    int s = csr_src[lo + lane];
                    s_src[lane] = s;
                    float4 a = as4[s];
                    e0 = lrelu(a.x + ad.x); e1 = lrelu(a.y + ad.y);
                    e2 = lrelu(a.z + ad.z); e3 = lrelu(a.w + ad.w);
                }
                float M0 = wmax(e0), M1 = wmax(e1), M2 = wmax(e2), M3 = wmax(e3);
                float p0 = __expf(e0 - M0), p1 = __expf(e1 - M1);
                float p2 = __expf(e2 - M2), p3 = __expf(e3 - M3);   // inactive -> 0
                float iz0 = 1.f / (wsum(p0) + 1e-16f), iz1 = 1.f / (wsum(p1) + 1e-16f);
                float iz2 = 1.f / (wsum(p2) + 1e-16f), iz3 = 1.f / (wsum(p3) + 1e-16f);
                if (lane < n) s_w[lane] = make_float4(p0 * iz0, p1 * iz1, p2 * iz2, p3 * iz3);
                int j = 0;
                for (; j + 4 <= n; j += 4) {   // 4 h-row loads in flight
                    int  q0 = s_src[j], q1 = s_src[j + 1], q2 = s_src[j + 2], q3 = s_src[j + 3];
                    float h0 = h_in[(size_t)q0 * HIDD + lane], h1 = h_in[(size_t)q1 * HIDD + lane];
                    float h2 = h_in[(size_t)q2 * HIDD + lane], h3 = h_in[(size_t)q3 * HIDD + lane];
                    float4 w0 = s_w[j], w1 = s_w[j + 1], w2 = s_w[j + 2], w3 = s_w[j + 3];
                    g0 += h0 * w0.x + h1 * w1.x + h2 * w2.x + h3 * w3.x;
                    g1 += h0 * w0.y + h1 * w1.y + h2 * w2.y + h3 * w3.y;
                    g2 += h0 * w0.z + h1 * w1.z + h2 * w2.z + h3 * w3.z;
                    g3 += h0 * w0.w + h1 * w1.w + h2 * w2.w + h3 * w3.w;
                }
                for (; j < n; ++j) {
                    float hv = h_in[(size_t)s_src[j] * HIDD + lane];
                    float4 w = s_w[j];
                    g0 += hv * w.x; g1 += hv * w.y; g2 += hv * w.z; g3 += hv * w.w;
                }
            } else {
                float m0 = -1e30f, m1 = -1e30f, m2 = -1e30f, m3 = -1e30f;
                for (int j = lane; j < n; j += 64) {
                    int s = csr_src[lo + j];
                    float4 a = as4[s];
                    m0 = fmaxf(m0, lrelu(a.x + ad.x)); m1 = fmaxf(m1, lrelu(a.y + ad.y));
                    m2 = fmaxf(m2, lrelu(a.z + ad.z)); m3 = fmaxf(m3, lrelu(a.w + ad.w));
                }
                m0 = wmax(m0); m1 = wmax(m1); m2 = wmax(m2); m3 = wmax(m3);
                float z0 = 0.f, z1 = 0.f, z2 = 0.f, z3 = 0.f;
                for (int j = lane; j < n; j += 64) {
                    int s = csr_src[lo + j];
                    float4 a = as4[s];
                    z0 += __expf(lrelu(a.x + ad.x) - m0); z1 += __expf(lrelu(a.y + ad.y) - m1);
                    z2 += __expf(lrelu(a.z + ad.z) - m2); z3 += __expf(lrelu(a.w + ad.w) - m3);
                }
                float iz0 = 1.f / (wsum(z0) + 1e-16f), iz1 = 1.f / (wsum(z1) + 1e-16f);
                float iz2 = 1.f / (wsum(z2) + 1e-16f), iz3 = 1.f / (wsum(z3) + 1e-16f);
                for (int cb = 0; cb < n; cb += 64) {
                    int nn = n - cb; if (nn > 64) nn = 64;
                    if (lane < nn) {
                        int s = csr_src[lo + cb + lane];
                        s_src[lane] = s;
                        float4 a = as4[s];
                        s_w[lane] = make_float4(__expf(lrelu(a.x + ad.x) - m0) * iz0,
                                                __expf(lrelu(a.y + ad.y) - m1) * iz1,
                                                __expf(lrelu(a.z + ad.z) - m2) * iz2,
                                                __expf(lrelu(a.w + ad.w) - m3) * iz3);
                    }
                    int j = 0;
                    for (; j + 4 <= nn; j += 4) {
                        int  q0 = s_src[j], q1 = s_src[j + 1], q2 = s_src[j + 2], q3 = s_src[j + 3];
                        float h0 = h_in[(size_t)q0 * HIDD + lane], h1 = h_in[(size_t)q1 * HIDD + lane];
                        float h2 = h_in[(size_t)q2 * HIDD + lane], h3 = h_in[(size_t)q3 * HIDD + lane];
                        float4 w0 = s_w[j], w1 = s_w[j + 1], w2 = s_w[j + 2], w3 = s_w[j + 3];
                        g0 += h0 * w0.x + h1 * w1.x + h2 * w2.x + h3 * w3.x;
                        g1 += h0 * w0.y + h1 * w1.y + h2 * w2.y + h3 * w3.y;
                        g2 += h0 * w0.z + h1 * w1.z + h2 * w2.z + h3 * w3.z;
                        g3 += h0 * w0.w + h1 * w1.w + h2 * w2.w + h3 * w3.w;
                    }
                    for (; j < nn; ++j) {
                        float hv = h_in[(size_t)s_src[j] * HIDD + lane];
                        float4 w = s_w[j];
                        g0 += hv * w.x; g1 += hv * w.y; g2 += hv * w.z; g3 += hv * w.w;
                    }
                }
            }
            const int r = wave * 4 + nd;
            s_in[r * HC + 0 * 64 + lane] = g0;
            s_in[r * HC + 1 * 64 + lane] = g1;
            s_in[r * HC + 2 * 64 + lane] = g2;
            s_in[r * HC + 3 * 64 + lane] = g3;
        }
    }
    __syncthreads();

    // ---- phase 2: GEMM1 mid = gelu(s_in @ W1eff + b1eff); 2 nodes x 4 f per thread ----
    const int fg = t & 31, ng2 = t >> 5;   // f = 4*fg.., nodes 2*ng2..2*ng2+1
    float4 acc1[2];
    acc1[0] = make_float4(0.f, 0.f, 0.f, 0.f);
    acc1[1] = make_float4(0.f, 0.f, 0.f, 0.f);
    {
        const float4* si4 = (const float4*)s_in;
        float4* sB4 = (float4*)s_buf;
        for (int kt = 0; kt < 4; ++kt) {
            __syncthreads();   // prior s_buf readers done (kt=0: gather scratch)
            const float4* gsrc = (const float4*)(W1eff + (size_t)kt * 64 * DFFD);
            for (int idx = t; idx < 2048; idx += 256) sB4[idx] = gsrc[idx];
            __syncthreads();
#pragma unroll 4
            for (int k4 = 0; k4 < 16; ++k4) {
                float4 w0 = sB4[(4 * k4 + 0) * 32 + fg];   // W1eff[k][4fg..4fg+3]
                float4 w1 = sB4[(4 * k4 + 1) * 32 + fg];
                float4 w2 = sB4[(4 * k4 + 2) * 32 + fg];
                float4 w3 = sB4[(4 * k4 + 3) * 32 + fg];
#pragma unroll
                for (int i = 0; i < 2; ++i) {
                    float4 v = si4[(2 * ng2 + i) * 64 + kt * 16 + k4];   // half-wave uniform
                    acc1[i].x += v.x * w0.x + v.y * w1.x + v.z * w2.x + v.w * w3.x;
                    acc1[i].y += v.x * w0.y + v.y * w1.y + v.z * w2.y + v.w * w3.y;
                    acc1[i].z += v.x * w0.z + v.y * w1.z + v.z * w2.z + v.w * w3.z;
                    acc1[i].w += v.x * w0.w + v.y * w1.w + v.z * w2.w + v.w * w3.w;
                }
            }
        }
    }
    __syncthreads();   // last tile consumed; s_buf becomes mid
    {
        float4 bb = *(const float4*)(b1eff + 4 * fg);
#pragma unroll
        for (int i = 0; i < 2; ++i) {
            float dx = acc1[i].x + bb.x, dy = acc1[i].y + bb.y;
            float dz = acc1[i].z + bb.z, dw = acc1[i].w + bb.w;
            ((float4*)s_buf)[(2 * ng2 + i) * 32 + fg] = make_float4(
                0.5f * dx * (1.f + erff(dx * 0.70710678118654752f)),
                0.5f * dy * (1.f + erff(dy * 0.70710678118654752f)),
                0.5f * dz * (1.f + erff(dz * 0.70710678118654752f)),
                0.5f * dw * (1.f + erff(dw * 0.70710678118654752f)));
        }
    }
    __syncthreads();

    // ---- phase 3: GEMM2 + LN + residual + next-layer attdots ----
    {
        const int w = t >> 6;   // wave w -> nodes 4w..4w+3, lane = channel
        float acc[4];
#pragma unroll
        for (int i = 0; i < 4; ++i) acc[i] = 0.f;
        const float4* sm4 = (const float4*)s_buf;
#pragma unroll 4
        for (int k4 = 0; k4 < 32; ++k4) {
            float w0 = W2[(4 * k4 + 0) * HIDD + lane];
            float w1 = W2[(4 * k4 + 1) * HIDD + lane];
            float w2 = W2[(4 * k4 + 2) * HIDD + lane];
            float w3 = W2[(4 * k4 + 3) * HIDD + lane];
#pragma unroll
            for (int i = 0; i < 4; ++i) {
                float4 v = sm4[(4 * w + i) * 32 + k4];   // wave-uniform broadcast
                acc[i] += v.x * w0 + v.y * w1 + v.z * w2 + v.w * w3;
            }
        }
        const float b2c = b2[lane], gc = ln_g[lane], bbc = ln_b[lane];
        float wr[8];
#pragma unroll
        for (int r = 0; r < 8; ++r) wr[r] = 0.f;
        if (ws_next) {
#pragma unroll
            for (int r = 0; r < 8; ++r) wr[r] = ws_next[r * 64 + lane];
        }
#pragma unroll
        for (int i = 0; i < 4; ++i) {
            int node = base + 4 * w + i;
            float d = acc[i] + b2c;
            float mean = wsum(d) * (1.0f / 64.0f);
            float dd = d - mean;
            float var = wsum(dd * dd) * (1.0f / 64.0f);
            float hv = h_in[(size_t)node * HIDD + lane] + dd * rsqrtf(var + 1e-5f) * gc + bbc;
            h_out[(size_t)node * HIDD + lane] = hv;
            if (ws_next) {
                float s0 = wsum(hv * wr[0]), s1 = wsum(hv * wr[1]);
                float s2 = wsum(hv * wr[2]), s3 = wsum(hv * wr[3]);
                float s4 = wsum(hv * wr[4]), s5 = wsum(hv * wr[5]);
                float s6 = wsum(hv * wr[6]), s7 = wsum(hv * wr[7]);
                if (lane == 0) {
                    ((float4*)a_s_out)[node] = make_float4(s0, s1, s2, s3);
                    ((float4*)a_d_out)[node] = make_float4(s4, s5, s6, s7);
                }
            }
        }
    }
}

extern "C" void kernel_launch(void* const* d_in, const int* in_sizes, int n_in,
                              void* d_out, int out_size, void* d_ws, size_t ws_size,
                              hipStream_t stream) {
    const float* x       = (const float*)d_in[0];
    const int*   ei      = (const int*)d_in[1];
    const float* We      = (const float*)d_in[2];
    const float* be      = (const float*)d_in[3];
    const float* Wc      = (const float*)d_in[4];
    const float* att_src = (const float*)d_in[5];
    const float* att_dst = (const float*)d_in[6];
    const float* bc      = (const float*)d_in[7];
    const float* W1      = (const float*)d_in[8];
    const float* b1      = (const float*)d_in[9];
    const float* W2      = (const float*)d_in[10];
    const float* b2      = (const float*)d_in[11];
    const float* ln_g    = (const float*)d_in[12];
    const float* ln_b    = (const float*)d_in[13];

    char* ws = (char*)d_ws;
    size_t off = 0;
    auto alloc = [&](size_t bytes) -> void* {
        void* p = ws + off; off += (bytes + 255) & ~(size_t)255; return p;
    };
    float* h0      = (float*)alloc((size_t)NN * HIDD * 4);
    float* h1      = (float*)alloc((size_t)NN * HIDD * 4);
    float* as0     = (float*)alloc((size_t)NN * NH * 4);
    float* ad0     = (float*)alloc((size_t)NN * NH * 4);
    float* as1     = (float*)alloc((size_t)NN * NH * 4);
    float* ad1     = (float*)alloc((size_t)NN * NH * 4);
    float* ws_all  = (float*)alloc((size_t)NL * 8 * 64 * 4);
    float* W1eff   = (float*)alloc((size_t)NL * HC * DFFD * 4);
    float* b1eff   = (float*)alloc((size_t)NL * DFFD * 4);
    int*   deg     = (int*)alloc((size_t)NN * 4);
    int*   rowptr  = (int*)alloc((size_t)(NN + 1) * 4);
    int*   cursor  = (int*)alloc((size_t)NN * 4);
    int*   csr_src = (int*)alloc((size_t)(NE + NN) * 4);
    (void)ws_size; (void)in_sizes; (void)n_in; (void)out_size;

    ws_kernel<<<8, 256, 0, stream>>>(Wc, att_src, att_dst, ws_all);
    w1eff_kernel<<<NL * 256, 128, 0, stream>>>(Wc, W1, W1eff);
    b1eff_kernel<<<NL, 128, 0, stream>>>(bc, W1, b1, b1eff);
    init_deg<<<(NN + 255) / 256, 256, 0, stream>>>(deg, cursor);
    embed_kernel<<<NN / 16, 256, 0, stream>>>(x, We, be, ws_all, h0, as0, ad0);
    count_edges<<<(NE + 255) / 256, 256, 0, stream>>>(ei, deg);
    scan_kernel<<<1, 1024, 0, stream>>>(deg, rowptr);
    scatter_edges<<<(NE + NN + 255) / 256, 256, 0, stream>>>(ei, rowptr, cursor, csr_src);

    for (int l = 0; l < NL; ++l) {
        const float* hi  = (l & 1) ? h1  : h0;
        const float* asi = (l & 1) ? as1 : as0;
        const float* adi = (l & 1) ? ad1 : ad0;
        float* ho  = (l == NL - 1) ? (float*)d_out : ((l & 1) ? h0 : h1);
        float* aso = (l & 1) ? as0 : as1;
        float* ado = (l & 1) ? ad0 : ad1;
        layer_kernel<<<NN / 16, 256, 0, stream>>>(hi, asi, adi, rowptr, csr_src,
            W1eff + (size_t)l * HC * DFFD, b1eff + (size_t)l * DFFD,
            W2 + (size_t)l * DFFD * HIDD, b2 + (size_t)l * HIDD,
            ln_g + (size_t)l * HIDD, ln_b + (size_t)l * HIDD,
            (l + 1 < NL) ? (ws_all + (size_t)(l + 1) * 8 * 64) : (const float*)nullptr,
            ho, aso, ado);
    }
}

// Round 9
// 497.763 us; speedup vs baseline: 3.4179x; 1.0230x over previous
//
#include <hip/hip_runtime.h>
#include <cmath>

#define NN   20000   // nodes
#define NE   320000  // edges (before self-loops)
#define IND  256
#define HIDD 64
#define NH   4
#define CD   64
#define HC   256     // NH*CD
#define DFFD 128
#define NL   4

// All float tensors are float32 (verified R1 vs R2). Output f32.
// R6 lesson: keep layer kernel at >=3 blocks/CU; occupancy beats LDS-op reduction.
// R7 lesson: profiled dispatch dur is inflated vs graph-replay wall clock; trust totals.
// R8 lesson: gather phase is latency-bound on per-edge dword loads -> widen to b128.

static __device__ __forceinline__ float lrelu(float v) { return v > 0.f ? v : 0.2f * v; }
static __device__ __forceinline__ float wsum(float v) { for (int k = 32; k; k >>= 1) v += __shfl_xor(v, k); return v; }
static __device__ __forceinline__ float wmax(float v) { for (int k = 32; k; k >>= 1) v = fmaxf(v, __shfl_xor(v, k)); return v; }
static __device__ __forceinline__ void fma4(float4& a, const float4& v, float s) {
    a.x += v.x * s; a.y += v.y * s; a.z += v.z * s; a.w += v.w * s;
}

// ---- ws_all[l][r][k]: r=0..3 -> Wc_head@att_src, r=4..7 -> Wc_head@att_dst ----
__global__ void ws_kernel(const float* __restrict__ Wc, const float* __restrict__ att_src,
                          const float* __restrict__ att_dst, float* __restrict__ ws_all) {
    int idx = blockIdx.x * 256 + threadIdx.x;   // 0..2047 = L*8*64
    int l = idx >> 9, r = (idx >> 6) & 7, k = idx & 63;
    int hh = r & 3;
    const float* att = ((r & 4) ? att_dst : att_src) + (size_t)l * NH * CD + hh * CD;
    const float* wrow = Wc + (size_t)l * HIDD * HC + (size_t)k * HC + hh * CD;
    float s = 0.f;
    for (int c = 0; c < CD; ++c) s += wrow[c] * att[c];
    ws_all[idx] = s;
}

// ---- W1eff[l][h*64+k][f] = sum_c Wc[l][k][h*64+c] * W1[l][h*64+c][f] ----
__global__ void w1eff_kernel(const float* __restrict__ Wc, const float* __restrict__ W1,
                             float* __restrict__ W1eff) {
    const int b = blockIdx.x;               // 0..NL*256-1
    const int l = b >> 8, hk = b & 255, hh = hk >> 6, kl = hk & 63;
    const int f = threadIdx.x;              // 0..127
    const float* wc = Wc + (size_t)l * HIDD * HC + (size_t)kl * HC + hh * 64;
    const float* w1 = W1 + (size_t)l * HC * DFFD + (size_t)(hh * 64) * DFFD + f;
    float s = 0.f;
#pragma unroll 4
    for (int c = 0; c < 64; ++c) s += wc[c] * w1[(size_t)c * DFFD];
    W1eff[(size_t)l * HC * DFFD + (size_t)hk * DFFD + f] = s;
}

// ---- b1eff[l][f] = b1[l][f] + sum_c bc[l][c] * W1[l][c][f] ----
__global__ void b1eff_kernel(const float* __restrict__ bc, const float* __restrict__ W1,
                             const float* __restrict__ b1, float* __restrict__ b1eff) {
    const int l = blockIdx.x, f = threadIdx.x;   // NL blocks x 128 threads
    const float* w1 = W1 + (size_t)l * HC * DFFD + f;
    const float* bcl = bc + (size_t)l * HC;
    float s = b1[(size_t)l * DFFD + f];
    for (int c = 0; c < HC; ++c) s += bcl[c] * w1[(size_t)c * DFFD];
    b1eff[l * DFFD + f] = s;
}

// ---- embed: h = (x @ We + be) * 8, fused layer-0 attention dots; 16 nodes/block ----
__global__ __launch_bounds__(256) void embed_kernel(const float* __restrict__ x,
                                                    const float* __restrict__ We,
                                                    const float* __restrict__ be,
                                                    const float* __restrict__ ws_all,
                                                    float* __restrict__ h,
                                                    float* __restrict__ a_s, float* __restrict__ a_d) {
    __shared__ float s_x[16 * IND];   // 16KB
    const int base = blockIdx.x * 16, t = threadIdx.x;
    for (int idx = t; idx < 16 * IND / 4; idx += 256)
        ((float4*)s_x)[idx] = ((const float4*)(x + (size_t)base * IND))[idx];
    __syncthreads();
    const int c = t & 63, g = t >> 6;   // wave g: nodes 4g..4g+3, lane = channel c
    float acc[4] = {0.f, 0.f, 0.f, 0.f};
    const float4* sx4 = (const float4*)s_x;
#pragma unroll 2
    for (int k4 = 0; k4 < IND / 4; ++k4) {
        float w0 = We[(4 * k4 + 0) * HIDD + c];
        float w1 = We[(4 * k4 + 1) * HIDD + c];
        float w2 = We[(4 * k4 + 2) * HIDD + c];
        float w3 = We[(4 * k4 + 3) * HIDD + c];
#pragma unroll
        for (int i = 0; i < 4; ++i) {
            float4 v = sx4[(4 * g + i) * (IND / 4) + k4];
            acc[i] += v.x * w0 + v.y * w1 + v.z * w2 + v.w * w3;
        }
    }
    float bias = be[c];
    float wr[8];
#pragma unroll
    for (int r = 0; r < 8; ++r) wr[r] = ws_all[r * 64 + c];   // layer 0
#pragma unroll
    for (int i = 0; i < 4; ++i) {
        int node = base + 4 * g + i;
        float hv = (acc[i] + bias) * 8.0f;
        h[(size_t)node * HIDD + c] = hv;
        float s0 = wsum(hv * wr[0]), s1 = wsum(hv * wr[1]);
        float s2 = wsum(hv * wr[2]), s3 = wsum(hv * wr[3]);
        float s4 = wsum(hv * wr[4]), s5 = wsum(hv * wr[5]);
        float s6 = wsum(hv * wr[6]), s7 = wsum(hv * wr[7]);
        if (c == 0) {
            ((float4*)a_s)[node] = make_float4(s0, s1, s2, s3);
            ((float4*)a_d)[node] = make_float4(s4, s5, s6, s7);
        }
    }
}

// ---------------- CSR build ----------------
__global__ void init_deg(int* __restrict__ deg, int* __restrict__ cursor) {
    int i = blockIdx.x * blockDim.x + threadIdx.x;
    if (i < NN) { deg[i] = 1; cursor[i] = 0; }   // self-loop
}

__global__ void count_edges(const int* __restrict__ ei, int* __restrict__ deg) {
    int e = blockIdx.x * blockDim.x + threadIdx.x;
    if (e < NE) atomicAdd(&deg[ei[NE + e]], 1);
}

__global__ void scan_kernel(const int* __restrict__ deg, int* __restrict__ rowptr) {
    __shared__ int part[1024];
    const int t = threadIdx.x;
    const int CH = (NN + 1023) / 1024;
    int lo = t * CH, hi = lo + CH; if (hi > NN) hi = NN;
    int s = 0;
    for (int i = lo; i < hi; ++i) s += deg[i];
    part[t] = s;
    __syncthreads();
    for (int off = 1; off < 1024; off <<= 1) {
        int v = 0;
        if (t >= off) v = part[t - off];
        __syncthreads();
        if (t >= off) part[t] += v;
        __syncthreads();
    }
    int base = (t == 0) ? 0 : part[t - 1];
    for (int i = lo; i < hi; ++i) { rowptr[i] = base; base += deg[i]; }
    if (lo <= NN - 1 && NN - 1 < hi) rowptr[NN] = base;
}

__global__ void scatter_edges(const int* __restrict__ ei, const int* __restrict__ rowptr,
                              int* __restrict__ cursor, int* __restrict__ csr_src) {
    int e = blockIdx.x * blockDim.x + threadIdx.x;
    if (e < NE) {
        int s = ei[e], d = ei[NE + e];
        int pos = atomicAdd(&cursor[d], 1);
        csr_src[rowptr[d] + pos] = s;
    } else if (e < NE + NN) {
        int i = e - NE;
        int pos = atomicAdd(&cursor[i], 1);
        csr_src[rowptr[i] + pos] = i;
    }
}

// ---- fused layer: gather/softmax-aggregate (wave-per-node, b128 edge loads) ->
//      GEMM1 -> GEMM2+LN+res. 16 nodes/block. Ping-pong h/a_s/a_d across layers.
// LDS: s_in 16KB + s_buf 32KB (gather scratch -> W1eff k-tiles -> mid) = 48KB -> 3 blk/CU.
__global__ __launch_bounds__(256, 3) void layer_kernel(
    const float* __restrict__ h_in, const float* __restrict__ a_s_in, const float* __restrict__ a_d_in,
    const int* __restrict__ rowptr, const int* __restrict__ csr_src,
    const float* __restrict__ W1eff, const float* __restrict__ b1eff,
    const float* __restrict__ W2, const float* __restrict__ b2,
    const float* __restrict__ ln_g, const float* __restrict__ ln_b,
    const float* __restrict__ ws_next,
    float* __restrict__ h_out, float* __restrict__ a_s_out, float* __restrict__ a_d_out) {
    __shared__ float s_in[16 * HC];   // 16KB aggregated node vectors
    __shared__ float s_buf[8192];     // 32KB: gather scratch -> W1eff tile -> mid
    const int base = blockIdx.x * 16, t = threadIdx.x, wave = t >> 6, lane = t & 63;

    // ---- phase 1: softmax-attention aggregation, wave-synchronous, 4 nodes/wave ----
    // Edge loop layout: lane = (eg = lane>>4, cg = lane&15); one b128 load covers
    // 4 edges x 4 channels -> 1KB/wave/instr; 4 head-accumulators (float4) per lane;
    // eg-butterfly (shfl_xor 16/32) completes channel sums; lane writes s_in4[r*64+lane].
    {
        int*    s_src = (int*)s_buf + wave * 64;             // per-wave [64]
        float4* s_w   = (float4*)(s_buf + 256) + wave * 64;  // per-wave [64]
        const float4* as4 = (const float4*)a_s_in;
        const float4* h4  = (const float4*)h_in;
        const int eg = lane >> 4, cg = lane & 15;
        for (int nd = 0; nd < 4; ++nd) {
            const int node = base + wave * 4 + nd;
            const int lo = rowptr[node], n = rowptr[node + 1] - lo;
            const float4 ad = ((const float4*)a_d_in)[node];
            float4 a0 = make_float4(0.f, 0.f, 0.f, 0.f);
            float4 a1 = a0, a2 = a0, a3 = a0;
            if (n <= 64) {
                float e0 = -1e30f, e1 = -1e30f, e2 = -1e30f, e3 = -1e30f;
                if (lane < n) {
                    int s = csr_src[lo + lane];
                    s_src[lane] = s;
                    float4 a = as4[s];
                    e0 = lrelu(a.x + ad.x); e1 = lrelu(a.y + ad.y);
                    e2 = lrelu(a.z + ad.z); e3 = lrelu(a.w + ad.w);
                }
                float M0 = wmax(e0), M1 = wmax(e1), M2 = wmax(e2), M3 = wmax(e3);
                float p0 = __expf(e0 - M0), p1 = __expf(e1 - M1);
                float p2 = __expf(e2 - M2), p3 = __expf(e3 - M3);   // inactive -> 0
                float iz0 = 1.f / (wsum(p0) + 1e-16f), iz1 = 1.f / (wsum(p1) + 1e-16f);
                float iz2 = 1.f / (wsum(p2) + 1e-16f), iz3 = 1.f / (wsum(p3) + 1e-16f);
                if (lane < n) s_w[lane] = make_float4(p0 * iz0, p1 * iz1, p2 * iz2, p3 * iz3);
                const int n8 = (n + 7) & ~7;
                if (lane >= n && lane < n8) {   // zero-weight padding, guard-free loop
                    s_src[lane] = s_src[0];
                    s_w[lane] = make_float4(0.f, 0.f, 0.f, 0.f);
                }
                for (int j = 0; j < n8; j += 8) {   // 8 edges in flight per iter
                    int sA = s_src[j + eg],     sB = s_src[j + 4 + eg];
                    float4 vA = h4[(size_t)sA * 16 + cg];
                    float4 vB = h4[(size_t)sB * 16 + cg];
                    float4 wA = s_w[j + eg],    wB = s_w[j + 4 + eg];
                    fma4(a0, vA, wA.x); fma4(a1, vA, wA.y); fma4(a2, vA, wA.z); fma4(a3, vA, wA.w);
                    fma4(a0, vB, wB.x); fma4(a1, vB, wB.y); fma4(a2, vB, wB.z); fma4(a3, vB, wB.w);
                }
            } else {
                // slow path (deg > 64): two-pass softmax, then chunked b128 gather
                float m0 = -1e30f, m1 = -1e30f, m2 = -1e30f, m3 = -1e30f;
                for (int j = lane; j < n; j += 64) {
                    int s = csr_src[lo + j];
                    float4 a = as4[s];
                    m0 = fmaxf(m0, lrelu(a.x + ad.x)); m1 = fmaxf(m1, lrelu(a.y + ad.y));
                    m2 = fmaxf(m2, lrelu(a.z + ad.z)); m3 = fmaxf(m3, lrelu(a.w + ad.w));
                }
                m0 = wmax(m0); m1 = wmax(m1); m2 = wmax(m2); m3 = wmax(m3);
                float z0 = 0.f, z1 = 0.f, z2 = 0.f, z3 = 0.f;
                for (int j = lane; j < n; j += 64) {
                    int s = csr_src[lo + j];
                    float4 a = as4[s];
                    z0 += __expf(lrelu(a.x + ad.x) - m0); z1 += __expf(lrelu(a.y + ad.y) - m1);
                    z2 += __expf(lrelu(a.z + ad.z) - m2); z3 += __expf(lrelu(a.w + ad.w) - m3);
                }
                float iz0 = 1.f / (wsum(z0) + 1e-16f), iz1 = 1.f / (wsum(z1) + 1e-16f);
                float iz2 = 1.f / (wsum(z2) + 1e-16f), iz3 = 1.f / (wsum(z3) + 1e-16f);
                for (int cb = 0; cb < n; cb += 64) {
                    int nn = n - cb; if (nn > 64) nn = 64;
                    if (lane < nn) {
                        int s = csr_src[lo + cb + lane];
                        s_src[lane] = s;
                        float4 a = as4[s];
                        s_w[lane] = make_float4(__expf(lrelu(a.x + ad.x) - m0) * iz0,
                                                __expf(lrelu(a.y + ad.y) - m1) * iz1,
                                                __expf(lrelu(a.z + ad.z) - m2) * iz2,
                                                __expf(lrelu(a.w + ad.w) - m3) * iz3);
                    }
                    const int nn8 = (nn + 7) & ~7;   // <= 64
                    if (lane >= nn && lane < nn8) {
                        s_src[lane] = s_src[0];
                        s_w[lane] = make_float4(0.f, 0.f, 0.f, 0.f);
                    }
                    for (int j = 0; j < nn8; j += 8) {
                        int sA = s_src[j + eg],     sB = s_src[j + 4 + eg];
                        float4 vA = h4[(size_t)sA * 16 + cg];
                        float4 vB = h4[(size_t)sB * 16 + cg];
                        float4 wA = s_w[j + eg],    wB = s_w[j + 4 + eg];
                        fma4(a0, vA, wA.x); fma4(a1, vA, wA.y); fma4(a2, vA, wA.z); fma4(a3, vA, wA.w);
                        fma4(a0, vB, wB.x); fma4(a1, vB, wB.y); fma4(a2, vB, wB.z); fma4(a3, vB, wB.w);
                    }
                }
            }
            // butterfly over eg bits (lanes 16/32 apart share channel group cg)
#pragma unroll
            for (int m = 16; m <= 32; m <<= 1) {
                a0.x += __shfl_xor(a0.x, m); a0.y += __shfl_xor(a0.y, m);
                a0.z += __shfl_xor(a0.z, m); a0.w += __shfl_xor(a0.w, m);
                a1.x += __shfl_xor(a1.x, m); a1.y += __shfl_xor(a1.y, m);
                a1.z += __shfl_xor(a1.z, m); a1.w += __shfl_xor(a1.w, m);
                a2.x += __shfl_xor(a2.x, m); a2.y += __shfl_xor(a2.y, m);
                a2.z += __shfl_xor(a2.z, m); a2.w += __shfl_xor(a2.w, m);
                a3.x += __shfl_xor(a3.x, m); a3.y += __shfl_xor(a3.y, m);
                a3.z += __shfl_xor(a3.z, m); a3.w += __shfl_xor(a3.w, m);
            }
            const int r = wave * 4 + nd;
            float4* si4 = (float4*)s_in;
            float4 outv = (eg == 0) ? a0 : (eg == 1) ? a1 : (eg == 2) ? a2 : a3;
            si4[r * 64 + lane] = outv;   // channel block eg*64 + 4*cg  == lane*4
        }
    }
    __syncthreads();

    // ---- phase 2: GEMM1 mid = gelu(s_in @ W1eff + b1eff); 2 nodes x 4 f per thread ----
    const int fg = t & 31, ng2 = t >> 5;   // f = 4*fg.., nodes 2*ng2..2*ng2+1
    float4 acc1[2];
    acc1[0] = make_float4(0.f, 0.f, 0.f, 0.f);
    acc1[1] = make_float4(0.f, 0.f, 0.f, 0.f);
    {
        const float4* si4 = (const float4*)s_in;
        float4* sB4 = (float4*)s_buf;
        for (int kt = 0; kt < 4; ++kt) {
            __syncthreads();   // prior s_buf readers done (kt=0: gather scratch)
            const float4* gsrc = (const float4*)(W1eff + (size_t)kt * 64 * DFFD);
            for (int idx = t; idx < 2048; idx += 256) sB4[idx] = gsrc[idx];
            __syncthreads();
#pragma unroll 4
            for (int k4 = 0; k4 < 16; ++k4) {
                float4 w0 = sB4[(4 * k4 + 0) * 32 + fg];   // W1eff[k][4fg..4fg+3]
                float4 w1 = sB4[(4 * k4 + 1) * 32 + fg];
                float4 w2 = sB4[(4 * k4 + 2) * 32 + fg];
                float4 w3 = sB4[(4 * k4 + 3) * 32 + fg];
#pragma unroll
                for (int i = 0; i < 2; ++i) {
                    float4 v = si4[(2 * ng2 + i) * 64 + kt * 16 + k4];   // half-wave uniform
                    acc1[i].x += v.x * w0.x + v.y * w1.x + v.z * w2.x + v.w * w3.x;
                    acc1[i].y += v.x * w0.y + v.y * w1.y + v.z * w2.y + v.w * w3.y;
                    acc1[i].z += v.x * w0.z + v.y * w1.z + v.z * w2.z + v.w * w3.z;
                    acc1[i].w += v.x * w0.w + v.y * w1.w + v.z * w2.w + v.w * w3.w;
                }
            }
        }
    }
    __syncthreads();   // last tile consumed; s_buf becomes mid
    {
        float4 bb = *(const float4*)(b1eff + 4 * fg);
#pragma unroll
        for (int i = 0; i < 2; ++i) {
            float dx = acc1[i].x + bb.x, dy = acc1[i].y + bb.y;
            float dz = acc1[i].z + bb.z, dw = acc1[i].w + bb.w;
            ((float4*)s_buf)[(2 * ng2 + i) * 32 + fg] = make_float4(
                0.5f * dx * (1.f + erff(dx * 0.70710678118654752f)),
                0.5f * dy * (1.f + erff(dy * 0.70710678118654752f)),
                0.5f * dz * (1.f + erff(dz * 0.70710678118654752f)),
                0.5f * dw * (1.f + erff(dw * 0.70710678118654752f)));
        }
    }
    __syncthreads();

    // ---- phase 3: GEMM2 + LN + residual + next-layer attdots ----
    {
        const int w = t >> 6;   // wave w -> nodes 4w..4w+3, lane = channel
        float acc[4];
#pragma unroll
        for (int i = 0; i < 4; ++i) acc[i] = 0.f;
        const float4* sm4 = (const float4*)s_buf;
#pragma unroll 4
        for (int k4 = 0; k4 < 32; ++k4) {
            float w0 = W2[(4 * k4 + 0) * HIDD + lane];
            float w1 = W2[(4 * k4 + 1) * HIDD + lane];
            float w2 = W2[(4 * k4 + 2) * HIDD + lane];
            float w3 = W2[(4 * k4 + 3) * HIDD + lane];
#pragma unroll
            for (int i = 0; i < 4; ++i) {
                float4 v = sm4[(4 * w + i) * 32 + k4];   // wave-uniform broadcast
                acc[i] += v.x * w0 + v.y * w1 + v.z * w2 + v.w * w3;
            }
        }
        const float b2c = b2[lane], gc = ln_g[lane], bbc = ln_b[lane];
        float wr[8];
#pragma unroll
        for (int r = 0; r < 8; ++r) wr[r] = 0.f;
        if (ws_next) {
#pragma unroll
            for (int r = 0; r < 8; ++r) wr[r] = ws_next[r * 64 + lane];
        }
#pragma unroll
        for (int i = 0; i < 4; ++i) {
            int node = base + 4 * w + i;
            float d = acc[i] + b2c;
            float mean = wsum(d) * (1.0f / 64.0f);
            float dd = d - mean;
            float var = wsum(dd * dd) * (1.0f / 64.0f);
            float hv = h_in[(size_t)node * HIDD + lane] + dd * rsqrtf(var + 1e-5f) * gc + bbc;
            h_out[(size_t)node * HIDD + lane] = hv;
            if (ws_next) {
                float s0 = wsum(hv * wr[0]), s1 = wsum(hv * wr[1]);
                float s2 = wsum(hv * wr[2]), s3 = wsum(hv * wr[3]);
                float s4 = wsum(hv * wr[4]), s5 = wsum(hv * wr[5]);
                float s6 = wsum(hv * wr[6]), s7 = wsum(hv * wr[7]);
                if (lane == 0) {
                    ((float4*)a_s_out)[node] = make_float4(s0, s1, s2, s3);
                    ((float4*)a_d_out)[node] = make_float4(s4, s5, s6, s7);
                }
            }
        }
    }
}

extern "C" void kernel_launch(void* const* d_in, const int* in_sizes, int n_in,
                              void* d_out, int out_size, void* d_ws, size_t ws_size,
                              hipStream_t stream) {
    const float* x       = (const float*)d_in[0];
    const int*   ei      = (const int*)d_in[1];
    const float* We      = (const float*)d_in[2];
    const float* be      = (const float*)d_in[3];
    const float* Wc      = (const float*)d_in[4];
    const float* att_src = (const float*)d_in[5];
    const float* att_dst = (const float*)d_in[6];
    const float* bc      = (const float*)d_in[7];
    const float* W1      = (const float*)d_in[8];
    const float* b1      = (const float*)d_in[9];
    const float* W2      = (const float*)d_in[10];
    const float* b2      = (const float*)d_in[11];
    const float* ln_g    = (const float*)d_in[12];
    const float* ln_b    = (const float*)d_in[13];

    char* ws = (char*)d_ws;
    size_t off = 0;
    auto alloc = [&](size_t bytes) -> void* {
        void* p = ws + off; off += (bytes + 255) & ~(size_t)255; return p;
    };
    float* h0      = (float*)alloc((size_t)NN * HIDD * 4);
    float* h1      = (float*)alloc((size_t)NN * HIDD * 4);
    float* as0     = (float*)alloc((size_t)NN * NH * 4);
    float* ad0     = (float*)alloc((size_t)NN * NH * 4);
    float* as1     = (float*)alloc((size_t)NN * NH * 4);
    float* ad1     = (float*)alloc((size_t)NN * NH * 4);
    float* ws_all  = (float*)alloc((size_t)NL * 8 * 64 * 4);
    float* W1eff   = (float*)alloc((size_t)NL * HC * DFFD * 4);
    float* b1eff   = (float*)alloc((size_t)NL * DFFD * 4);
    int*   deg     = (int*)alloc((size_t)NN * 4);
    int*   rowptr  = (int*)alloc((size_t)(NN + 1) * 4);
    int*   cursor  = (int*)alloc((size_t)NN * 4);
    int*   csr_src = (int*)alloc((size_t)(NE + NN) * 4);
    (void)ws_size; (void)in_sizes; (void)n_in; (void)out_size;

    ws_kernel<<<8, 256, 0, stream>>>(Wc, att_src, att_dst, ws_all);
    w1eff_kernel<<<NL * 256, 128, 0, stream>>>(Wc, W1, W1eff);
    b1eff_kernel<<<NL, 128, 0, stream>>>(bc, W1, b1, b1eff);
    init_deg<<<(NN + 255) / 256, 256, 0, stream>>>(deg, cursor);
    embed_kernel<<<NN / 16, 256, 0, stream>>>(x, We, be, ws_all, h0, as0, ad0);
    count_edges<<<(NE + 255) / 256, 256, 0, stream>>>(ei, deg);
    scan_kernel<<<1, 1024, 0, stream>>>(deg, rowptr);
    scatter_edges<<<(NE + NN + 255) / 256, 256, 0, stream>>>(ei, rowptr, cursor, csr_src);

    for (int l = 0; l < NL; ++l) {
        const float* hi  = (l & 1) ? h1  : h0;
        const float* asi = (l & 1) ? as1 : as0;
        const float* adi = (l & 1) ? ad1 : ad0;
        float* ho  = (l == NL - 1) ? (float*)d_out : ((l & 1) ? h0 : h1);
        float* aso = (l & 1) ? as0 : as1;
        float* ado = (l & 1) ? ad0 : ad1;
        layer_kernel<<<NN / 16, 256, 0, stream>>>(hi, asi, adi, rowptr, csr_src,
            W1eff + (size_t)l * HC * DFFD, b1eff + (size_t)l * DFFD,
            W2 + (size_t)l * DFFD * HIDD, b2 + (size_t)l * HIDD,
            ln_g + (size_t)l * HIDD, ln_b + (size_t)l * HIDD,
            (l + 1 < NL) ? (ws_all + (size_t)(l + 1) * 8 * 64) : (const float*)nullptr,
            ho, aso, ado);
    }
}